// Round 12
// baseline (627.299 us; speedup 1.0000x reference)
//
#include <hip/hip_runtime.h>
#include <hip/hip_bf16.h>

#define NTOT 4194304
typedef __attribute__((ext_vector_type(4)))  short short4v;
typedef __attribute__((ext_vector_type(8)))  short short8v;
typedef __attribute__((ext_vector_type(4)))  float f32x4;

__device__ __forceinline__ ushort f2bf(float f){
    __hip_bfloat16 h = __float2bfloat16(f);
    return __bfloat16_as_ushort(h);
}
__device__ __forceinline__ float bf2f(ushort u){
    return __uint_as_float(((unsigned)u)<<16);
}

// ---------------- weight pack: per-lane MFMA B-fragment order, bf16 ----------------
// dwPk[l][ciq4][kkp5][koff2][cih2][jg2][co64][j4]
// owPk[l][ciq4][kkp5][koff2][cih2][jg2][co32][j4]
__global__ __launch_bounds__(256) void pack_w(
    const float* __restrict__ dw, const float* __restrict__ ow,
    ushort* __restrict__ dwPk, ushort* __restrict__ owPk,
    float* __restrict__ statsG)
{
    int i = blockIdx.x*256 + threadIdx.x;
    if (i < 286720) {
        int j = i&3, co = (i>>2)&63, jg=(i>>8)&1, cih=(i>>9)&1, koff=(i>>10)&1;
        int r = i>>11; int kkp = r%5; int r2 = r/5; int ciq = r2&3; int l = r2>>2;
        int kk = kkp*2+koff, ci = ciq*16 + cih*8 + jg*4 + j;
        float v = (kk<9)? dw[((l*64+co)*64+ci)*9+kk] : 0.f;
        dwPk[i] = f2bf(v);
    }
    if (i < 143360) {
        int j = i&3, co = (i>>2)&31, jg=(i>>7)&1, cih=(i>>8)&1, koff=(i>>9)&1;
        int r = i>>10; int kkp = r%5; int r2 = r/5; int ciq = r2&3; int l = r2>>2;
        int kk = kkp*2+koff, ci = ciq*16 + cih*8 + jg*4 + j;
        float v = (kk<9 && co<18)? ow[((l*18+co)*64+ci)*9+kk] : 0.f;
        owPk[i] = f2bf(v);
    }
    if (i < 7*1024) statsG[i] = 0.f;   // zero stats accumulators (capture-safe)
}

// ---------------- per-layer transpose: NCHW f32 -> [b][y][x][ci] bf16 ----------------
__global__ __launch_bounds__(256) void transpose_x(
    const float* __restrict__ src, ushort* __restrict__ xT)
{
    __shared__ ushort lds[128*72];   // [x 128][ci 72pad]
    const int bid = blockIdx.x, t = threadIdx.x;
    const int b = bid>>7, y = bid&127;
    const float* sp = src + (b<<20) + (y<<7);
#pragma unroll
    for (int i=0;i<32;i++){
        int lin = i*256 + t;
        int ci = lin>>7, xx = lin&127;
        lds[xx*72 + ci] = f2bf(sp[(ci<<14) + xx]);
    }
    __syncthreads();
    ushort* dp = xT + (((b<<7)+y)<<13);
#pragma unroll
    for (int i=0;i<4;i++){
        int u = i*256 + t;
        int xx = u>>3, cg = u&7;
        short8v v8 = *(const short8v*)(lds + xx*72 + cg*8);
        *(short8v*)(dp + (xx<<6) + cg*8) = v8;
    }
}

// kh/kw tables; index 9 clamps to kk=8 (ghost K-slots carry zero weights)
__constant__ int KHt[10] = {0,0,0,1,1,1,2,2,2,2};
__constant__ int KWt[10] = {0,1,2,0,1,2,0,1,2,2};

// ---------------- fused offset-conv + deformable conv, K-SPLIT across waves ----------------
// Block: 256 thr = 4 waves = (2 pixel-rows) x (2 ci-halves); tile 2 rows x 32 cols.
// Wave: 32 px (2 A-frags), ciq in {0,1} (cisplit 0) or {2,3} (cisplit 1).
// Grid 1024 -> 4 blocks/CU = 16 waves/CU (round 11 was grid-limited at 8).
// Partials reconcile in LDS: offl[2 planes] (pass 2 sums), yt[2 planes] (epilogue sums).
// Corners gathered b128 from channel-last xT (exact reference semantics, no fallback).
// A-frag lane: pixel = p*16+(lane&15); k-slot: kk=2kkp+(lane>>5), ci=ciq*16+8*((lane>>4)&1)+j.
// C/D: col=lane&15 (co), row=(lane>>4)*4+reg (pix).
__global__ __attribute__((amdgpu_flat_work_group_size(256,256)))
void dcn_layer(
    const ushort* __restrict__ xT, const ushort* __restrict__ owPk,
    const float* __restrict__ ob, const ushort* __restrict__ dwPk,
    ushort* __restrict__ yb, float* __restrict__ statsL)
{
    __shared__ __align__(16) char smem[19456];
    float* offl = (float*)smem;              // [2 planes][64 px][20] f32 = 10240 B

    const int t = threadIdx.x, lane = t&63, w = t>>6;
    const int l15 = lane&15, lg = lane>>4;
    const int cih = lg&1, koff = lane>>5;
    const int prow = w&1, cisplit = w>>1;    // wave role
    const int bid = blockIdx.x;
    const int xcd = bid&7, idx = bid>>3;
    const int b = xcd>>1, vh = xcd&1;
    const int ht = vh*32 + (idx>>2), wt = idx&3;
    const int w0 = wt*32, h0 = ht*2;
    const int row = h0 + prow;
    const ushort* xb = xT + (b<<20);         // batch slab

    // ================= pass 1: offset conv via MFMA (partial over 2 ciq) =================
    f32x4 oacc[2][2];
#pragma unroll
    for (int p=0;p<2;p++)
#pragma unroll
        for (int q=0;q<2;q++) oacc[p][q] = (f32x4){0.f,0.f,0.f,0.f};

#pragma unroll 1
    for (int kkp=0; kkp<5; ++kkp) {
        int kkA = 2*kkp;
        int kkB = (kkA+1>8)?8:(kkA+1);
        int kh = koff ? KHt[kkB] : KHt[kkA];
        int kw = koff ? KWt[kkB] : KWt[kkA];
        int gy = row + kh - 1;
        bool vy = ((unsigned)gy<128u);
        int gyc = min(max(gy,0),127);
        int ebase[2]; bool okp[2];
#pragma unroll
        for (int p=0;p<2;p++){
            int gx = w0 + p*16 + l15 + kw - 1;
            okp[p] = vy && ((unsigned)gx<128u);
            int gxc = min(max(gx,0),127);
            ebase[p] = (((gyc<<7)+gxc)<<6) + cih*8;
        }
        const short8v zz = (short8v){0,0,0,0,0,0,0,0};
#pragma unroll
        for (int cc=0; cc<2; ++cc) {
            int ciq = cisplit*2 + cc;
            short8v afr[2];
#pragma unroll
            for (int p=0;p<2;p++){
                short8v q = *(const short8v*)(xb + ebase[p] + ciq*16);
                afr[p] = okp[p] ? q : zz;
            }
            const ushort* wop = owPk + ciq*5120 + kkp*1024 + koff*512 + cih*256;
#pragma unroll
            for (int q=0;q<2;q++){
                short4v b0 = *(const short4v*)(wop +       (q*16+l15)*4);
                short4v b1 = *(const short4v*)(wop + 128 + (q*16+l15)*4);
                short8v bb = __builtin_shufflevector(b0,b1,0,1,2,3,4,5,6,7);
#pragma unroll
                for (int p=0;p<2;p++)
                    oacc[p][q] = __builtin_amdgcn_mfma_f32_16x16x32_bf16(afr[p], bb, oacc[p][q], 0,0,0);
            }
        }
    }

    // partial offsets -> offl[cisplit][pix 64][20]; bias only into plane 0
    {
        float biasq[2];
#pragma unroll
        for (int q=0;q<2;q++){
            int o = q*16+l15;
            biasq[q] = (cisplit==0 && o<18)? ob[o] : 0.f;
        }
        float* pl = offl + cisplit*1280;
#pragma unroll
        for (int p=0;p<2;p++)
#pragma unroll
            for (int q=0;q<2;q++){
                int o = q*16+l15;
                if (o < 18) {
#pragma unroll
                    for (int r=0;r<4;r++){
                        int pix = prow*32 + p*16 + lg*4 + r;
                        pl[pix*20 + o] = oacc[p][q][r] + biasq[q];
                    }
                }
            }
    }
    __syncthreads();

    // ================= pass 2: deformable conv via MFMA (partial over 2 ciq) =================
    f32x4 acc[2][4];
#pragma unroll
    for (int p=0;p<2;p++)
#pragma unroll
        for (int q=0;q<4;q++) acc[p][q] = (f32x4){0.f,0.f,0.f,0.f};

#pragma unroll 1
    for (int kkp=0; kkp<5; ++kkp) {
        int kkA = 2*kkp;
        int kkB = (kkA+1>8)?8:(kkA+1);
        int kh = koff ? KHt[kkB] : KHt[kkA];
        int kw = koff ? KWt[kkB] : KWt[kkA];
        int kkX = koff ? kkB : kkA;

        // hoisted (ci-invariant) bilinear per A-frag: weights + corner bases
        float f00a[2],f01a[2],f10a[2],f11a[2];
        int e00a[2],e01a[2],e10a[2],e11a[2];
#pragma unroll
        for (int p=0;p<2;p++){
            int pix = prow*32 + p*16 + l15;
            float2 od0 = *(const float2*)(offl +        pix*20 + 2*kkX);
            float2 od1 = *(const float2*)(offl + 1280 + pix*20 + 2*kkX);
            float py = (float)(row + kh - 1) + od0.x + od1.x;
            float px = (float)(w0 + p*16 + l15 + kw - 1) + od0.y + od1.y;
            float fy = floorf(py), fx = floorf(px);
            float ly = py - fy, lx = px - fx;
            int y0 = (int)fy, x0 = (int)fx;
            int y1 = y0+1, x1 = x0+1;
            bool vy0 = ((unsigned)y0<128u), vy1 = ((unsigned)y1<128u);
            bool vx0 = ((unsigned)x0<128u), vx1 = ((unsigned)x1<128u);
            int y0c = min(max(y0,0),127), y1c = min(max(y1,0),127);
            int x0c = min(max(x0,0),127), x1c = min(max(x1,0),127);
            f00a[p] = (vy0&&vx0) ? (1.f-ly)*(1.f-lx) : 0.f;
            f01a[p] = (vy0&&vx1) ? (1.f-ly)*lx       : 0.f;
            f10a[p] = (vy1&&vx0) ? ly*(1.f-lx)       : 0.f;
            f11a[p] = (vy1&&vx1) ? ly*lx             : 0.f;
            e00a[p] = (((y0c<<7)+x0c)<<6) + cih*8;
            e01a[p] = (((y0c<<7)+x1c)<<6) + cih*8;
            e10a[p] = (((y1c<<7)+x0c)<<6) + cih*8;
            e11a[p] = (((y1c<<7)+x1c)<<6) + cih*8;
        }

#pragma unroll
        for (int cc=0; cc<2; ++cc) {
            int ciq = cisplit*2 + cc;
            short8v afr[2];
#pragma unroll
            for (int p=0;p<2;p++){
                short8v q00 = *(const short8v*)(xb + e00a[p] + ciq*16);
                short8v q01 = *(const short8v*)(xb + e01a[p] + ciq*16);
                short8v q10 = *(const short8v*)(xb + e10a[p] + ciq*16);
                short8v q11 = *(const short8v*)(xb + e11a[p] + ciq*16);
                float sv[8];
#pragma unroll
                for (int j=0;j<8;j++)
                    sv[j] = f00a[p]*bf2f((ushort)q00[j]) + f01a[p]*bf2f((ushort)q01[j])
                          + f10a[p]*bf2f((ushort)q10[j]) + f11a[p]*bf2f((ushort)q11[j]);
#pragma unroll
                for (int j=0;j<8;j++) afr[p][j] = (short)f2bf(sv[j]);
            }
            const ushort* wp = dwPk + ciq*10240 + kkp*2048 + koff*1024 + cih*512;
#pragma unroll
            for (int q=0;q<4;q++){
                short4v b0 = *(const short4v*)(wp +       (q*16+l15)*4);
                short4v b1 = *(const short4v*)(wp + 256 + (q*16+l15)*4);
                short8v bb = __builtin_shufflevector(b0,b1,0,1,2,3,4,5,6,7);
                acc[0][q] = __builtin_amdgcn_mfma_f32_16x16x32_bf16(afr[0], bb, acc[0][q], 0,0,0);
                acc[1][q] = __builtin_amdgcn_mfma_f32_16x16x32_bf16(afr[1], bb, acc[1][q], 0,0,0);
            }
        }
    }

    // ================= epilogue: sum ci-planes in LDS, bf16 store, stats =================
    float* yt  = (float*)smem;               // [2 planes][32 co][68] f32 = 17408 B
    float* red = (float*)(smem + 17408);     // 512 f32
#pragma unroll
    for (int half=0; half<2; ++half){
        __syncthreads();   // half0: offl reads done; half1: prev pass reads done
#pragma unroll
        for (int p=0;p<2;p++)
#pragma unroll
            for (int qq=0;qq<2;qq++)
                *(f32x4*)(yt + cisplit*2176 + (qq*16+l15)*68 + prow*32 + p*16 + lg*4)
                    = acc[p][half*2+qq];
        __syncthreads();
        {
            int co = t>>3, pxg = (t&7)*8;            // 32 co x 8 px-groups
            f32x4 a0 = *(const f32x4*)(yt + co*68 + pxg);
            f32x4 a1 = *(const f32x4*)(yt + co*68 + pxg + 4);
            f32x4 b0 = *(const f32x4*)(yt + 2176 + co*68 + pxg);
            f32x4 b1 = *(const f32x4*)(yt + 2176 + co*68 + pxg + 4);
            float s=0.f, s2=0.f;
            short8v v8;
#pragma unroll
            for (int e=0;e<4;e++){
                float v = a0[e]+b0[e];
                v8[e] = (short)f2bf(v); s += v; s2 += v*v;
            }
#pragma unroll
            for (int e=0;e<4;e++){
                float v = a1[e]+b1[e];
                v8[4+e] = (short)f2bf(v); s += v; s2 += v*v;
            }
            *(short8v*)(yb + ((((b<<6) + half*32 + co)<<14)
                        + ((h0 + (pxg>>5))<<7) + w0 + (pxg&31))) = v8;
            red[(t&7)*32 + (co&31)] = 0.f;   // (placeholder slot clear not needed; direct write below)
            red[(t&7)*32 + co - ((co>>5)<<5)] = s;      // co<32 always
            red[256 + (t&7)*32 + co] = s2;
            red[(t&7)*32 + co] = s;
        }
        __syncthreads();
        if (t < 64){
            int vv = t>>5, cc2 = t&31;
            float a = 0.f;
#pragma unroll
            for (int g=0;g<8;g++) a += red[vv*256 + g*32 + cc2];
            atomicAdd(statsL + (bid&7)*128 + vv*64 + half*32 + cc2, a);
        }
    }
}

// ---------------- normalize + ReLU + epilogue (yb is bf16) ----------------
// mode 0: out = relu(.)   mode 1: out = relu(.) + addsrc   mode 2: out += relu(.)
__global__ __launch_bounds__(256) void norm2(
    const ushort* __restrict__ yv, const float* __restrict__ statsL,
    const float* __restrict__ gamma, const float* __restrict__ beta,
    const float* __restrict__ addsrc, float* out, int mode)
{
    const int i8 = blockIdx.x*256 + threadIdx.x;   // 524288 total, 8 elems each
    const int ch = (i8 >> 11) & 63;
    float sum=0.f, ssq=0.f;
#pragma unroll
    for (int s=0;s<8;s++){ sum += statsL[s*128+ch]; ssq += statsL[s*128+64+ch]; }
    float mean = sum*(1.f/65536.f);
    float var  = ssq*(1.f/65536.f) - mean*mean;
    float inv  = rsqrtf(var + 1e-5f);
    float sc = gamma[ch]*inv, sh = beta[ch] - mean*sc;
    short8v v8 = *(const short8v*)(yv + i8*8);
    float r[8];
#pragma unroll
    for (int e=0;e<8;e++) r[e] = fmaxf(bf2f((ushort)v8[e])*sc+sh, 0.f);
    if (mode == 1) {
        const float4* ap = (const float4*)(addsrc + i8*8);
        float4 a0 = ap[0], a1 = ap[1];
        r[0]+=a0.x; r[1]+=a0.y; r[2]+=a0.z; r[3]+=a0.w;
        r[4]+=a1.x; r[5]+=a1.y; r[6]+=a1.z; r[7]+=a1.w;
    } else if (mode == 2) {
        const float4* op = (const float4*)(out + i8*8);
        float4 a0 = op[0], a1 = op[1];
        r[0]+=a0.x; r[1]+=a0.y; r[2]+=a0.z; r[3]+=a0.w;
        r[4]+=a1.x; r[5]+=a1.y; r[6]+=a1.z; r[7]+=a1.w;
    }
    float4* dp = (float4*)(out + i8*8);
    dp[0] = make_float4(r[0],r[1],r[2],r[3]);
    dp[1] = make_float4(r[4],r[5],r[6],r[7]);
}

// ---------------- host orchestration ----------------
extern "C" void kernel_launch(void* const* d_in, const int* in_sizes, int n_in,
                              void* d_out, int out_size, void* d_ws, size_t ws_size,
                              hipStream_t stream)
{
    const float* x  = (const float*)d_in[0];
    const float* ow = (const float*)d_in[1];
    const float* ob = (const float*)d_in[2];
    const float* dw = (const float*)d_in[3];
    const float* g  = (const float*)d_in[4];
    const float* be = (const float*)d_in[5];
    float* out = (float*)d_out;

    float*  P      = (float*)d_ws;
    float*  Q      = P + NTOT;
    ushort* ybBf   = (ushort*)(Q + NTOT);
    ushort* xT     = ybBf + NTOT;
    float*  statsG = (float*)(xT + NTOT);    // 7*1024 f32
    ushort* dwPk   = (ushort*)(statsG + 7*1024);
    ushort* owPk   = dwPk + 286720;

    pack_w<<<1120, 256, 0, stream>>>(dw, ow, dwPk, owPk, statsG);

    auto L = [&](int l, const float* in, float* dst, int mode, const float* adds){
        transpose_x<<<512, 256, 0, stream>>>(in, xT);
        dcn_layer<<<1024, 256, 0, stream>>>(xT, owPk + l*20480, ob + l*18,
                                            dwPk + l*40960, ybBf, statsG + l*1024);
        norm2<<<2048, 256, 0, stream>>>(ybBf, statsG + l*1024, g + l*64, be + l*64,
                                        adds, dst, mode);
    };

    L(0, x, P,   0, nullptr);   // P = L0(x)
    L(1, P, P,   0, nullptr);   // P = L1(P)            (out_1)
    L(4, x, Q,   1, P);         // Q = L4(x) + P        (out_sum_1)
    L(2, Q, P,   0, nullptr);   // P = L2(Q)
    L(3, P, out, 0, nullptr);   // out = L3(P)
    L(5, Q, out, 2, nullptr);   // out += L5(Q)
    L(6, Q, out, 2, nullptr);   // out += L6(Q)
}

// Round 13
// 582.808 us; speedup vs baseline: 1.0763x; 1.0763x over previous
//
#include <hip/hip_runtime.h>
#include <hip/hip_bf16.h>

#define NTOT 4194304
typedef __attribute__((ext_vector_type(4)))  short short4v;
typedef __attribute__((ext_vector_type(8)))  short short8v;
typedef __attribute__((ext_vector_type(4)))  float f32x4;

__device__ __forceinline__ ushort f2bf(float f){
    __hip_bfloat16 h = __float2bfloat16(f);
    return __bfloat16_as_ushort(h);
}
__device__ __forceinline__ float bf2f(ushort u){
    return __uint_as_float(((unsigned)u)<<16);
}

// ---------------- weight pack: per-lane MFMA B-fragment order, bf16 ----------------
// dwPk[l][ciq4][kkp5][koff2][cih2][jg2][co64][j4]
// owPk[l][ciq4][kkp5][koff2][cih2][jg2][co32][j4]
__global__ __launch_bounds__(256) void pack_w(
    const float* __restrict__ dw, const float* __restrict__ ow,
    ushort* __restrict__ dwPk, ushort* __restrict__ owPk,
    float* __restrict__ statsG)
{
    int i = blockIdx.x*256 + threadIdx.x;
    if (i < 286720) {
        int j = i&3, co = (i>>2)&63, jg=(i>>8)&1, cih=(i>>9)&1, koff=(i>>10)&1;
        int r = i>>11; int kkp = r%5; int r2 = r/5; int ciq = r2&3; int l = r2>>2;
        int kk = kkp*2+koff, ci = ciq*16 + cih*8 + jg*4 + j;
        float v = (kk<9)? dw[((l*64+co)*64+ci)*9+kk] : 0.f;
        dwPk[i] = f2bf(v);
    }
    if (i < 143360) {
        int j = i&3, co = (i>>2)&31, jg=(i>>7)&1, cih=(i>>8)&1, koff=(i>>9)&1;
        int r = i>>10; int kkp = r%5; int r2 = r/5; int ciq = r2&3; int l = r2>>2;
        int kk = kkp*2+koff, ci = ciq*16 + cih*8 + jg*4 + j;
        float v = (kk<9 && co<18)? ow[((l*18+co)*64+ci)*9+kk] : 0.f;
        owPk[i] = f2bf(v);
    }
    if (i < 7*1024) statsG[i] = 0.f;   // zero stats accumulators (capture-safe)
}

// ---------------- one-time transpose: NCHW f32 -> [b][y][x][ci] bf16 ----------------
__global__ __launch_bounds__(256) void transpose_x(
    const float* __restrict__ src, ushort* __restrict__ xT)
{
    __shared__ ushort lds[128*72];   // [x 128][ci 72pad]
    const int bid = blockIdx.x, t = threadIdx.x;
    const int b = bid>>7, y = bid&127;
    const float* sp = src + (b<<20) + (y<<7);
#pragma unroll
    for (int i=0;i<32;i++){
        int lin = i*256 + t;
        int ci = lin>>7, xx = lin&127;
        lds[xx*72 + ci] = f2bf(sp[(ci<<14) + xx]);
    }
    __syncthreads();
    ushort* dp = xT + (((b<<7)+y)<<13);
#pragma unroll
    for (int i=0;i<4;i++){
        int u = i*256 + t;
        int xx = u>>3, cg = u&7;
        short8v v8 = *(const short8v*)(lds + xx*72 + cg*8);
        *(short8v*)(dp + (xx<<6) + cg*8) = v8;
    }
}

// kh/kw tables; index 9 clamps to kk=8 (ghost K-slots carry zero weights)
__constant__ int KHt[10] = {0,0,0,1,1,1,2,2,2,2};
__constant__ int KWt[10] = {0,1,2,0,1,2,0,1,2,2};

// ---------------- fused offset-conv + deformable conv, 16 px/wave ----------------
// Block: 256 thr = 4 waves = (2 rows) x (2 col-halves); tile 2 rows x 32 cols = 64 px.
// Wave: 16 px (ONE A-frag), ALL 4 ciq (no K-split, no duplicated addr math).
// Grid 1024 -> 4096 waves = 16 waves/CU potential (r11 capped at 8 by 32px/wave).
// Corners gathered b128 from channel-last xT (exact reference semantics).
// LDS 10.7KB. ciq fully unrolled: 16 independent b128 loads in flight per kkp.
// A-frag lane: pixel = lane&15; k-slot: kk=2kkp+(lane>>5), ci=ciq*16+8*((lane>>4)&1)+j.
// C/D: col=lane&15 (co), row=(lane>>4)*4+reg (pix).
__global__ __attribute__((amdgpu_flat_work_group_size(256,256)))
void dcn_layer(
    const ushort* __restrict__ xT, const ushort* __restrict__ owPk,
    const float* __restrict__ ob, const ushort* __restrict__ dwPk,
    ushort* __restrict__ yb, float* __restrict__ statsL)
{
    __shared__ __align__(16) char smem[10752];
    float* offl = (float*)smem;              // [64 px][20] f32 = 5120 B

    const int t = threadIdx.x, lane = t&63, w = t>>6;
    const int l15 = lane&15, lg = lane>>4;
    const int cih = lg&1, koff = lane>>5;
    const int prow = w&1, chalf = w>>1;      // wave role: row, col-half
    const int bid = blockIdx.x;
    const int xcd = bid&7, idx = bid>>3;
    const int b = xcd>>1, vh = xcd&1;
    const int ht = vh*32 + (idx>>2), wt = idx&3;
    const int w0 = wt*32, h0 = ht*2;
    const int row = h0 + prow;
    const int cb = w0 + chalf*16;            // wave col base
    const ushort* xb = xT + (b<<20);

    // ================= pass 1: offset conv via MFMA =================
    f32x4 oacc[2];
    oacc[0] = (f32x4){0.f,0.f,0.f,0.f};
    oacc[1] = (f32x4){0.f,0.f,0.f,0.f};

#pragma unroll 1
    for (int kkp=0; kkp<5; ++kkp) {
        int kkA = 2*kkp;
        int kkB = (kkA+1>8)?8:(kkA+1);
        int kh = koff ? KHt[kkB] : KHt[kkA];
        int kw = koff ? KWt[kkB] : KWt[kkA];
        int gy = row + kh - 1;
        int gx = cb + l15 + kw - 1;
        bool ok = ((unsigned)gy<128u) && ((unsigned)gx<128u);
        int gyc = min(max(gy,0),127), gxc = min(max(gx,0),127);
        int ebase = (((gyc<<7)+gxc)<<6) + cih*8;
        const short8v zz = (short8v){0,0,0,0,0,0,0,0};
#pragma unroll
        for (int ciq=0; ciq<4; ++ciq) {
            short8v q = *(const short8v*)(xb + ebase + ciq*16);
            short8v afr = ok ? q : zz;
            const ushort* wop = owPk + ciq*5120 + kkp*1024 + koff*512 + cih*256;
#pragma unroll
            for (int q2=0;q2<2;q2++){
                short4v b0 = *(const short4v*)(wop +       (q2*16+l15)*4);
                short4v b1 = *(const short4v*)(wop + 128 + (q2*16+l15)*4);
                short8v bb = __builtin_shufflevector(b0,b1,0,1,2,3,4,5,6,7);
                oacc[q2] = __builtin_amdgcn_mfma_f32_16x16x32_bf16(afr, bb, oacc[q2], 0,0,0);
            }
        }
    }

    // redistribute offsets: offl[pix 64][20]; only o<18 (stride-20 overflow guard)
    {
        float biasq[2];
#pragma unroll
        for (int q=0;q<2;q++){ int o = q*16+l15; biasq[q] = (o<18)? ob[o] : 0.f; }
#pragma unroll
        for (int q=0;q<2;q++){
            int o = q*16+l15;
            if (o < 18) {
#pragma unroll
                for (int r=0;r<4;r++){
                    int pix = prow*32 + chalf*16 + lg*4 + r;
                    offl[pix*20 + o] = oacc[q][r] + biasq[q];
                }
            }
        }
    }
    __syncthreads();

    // ================= pass 2: deformable conv via MFMA =================
    f32x4 acc[4];
#pragma unroll
    for (int q=0;q<4;q++) acc[q] = (f32x4){0.f,0.f,0.f,0.f};

#pragma unroll 1
    for (int kkp=0; kkp<5; ++kkp) {
        int kkA = 2*kkp;
        int kkB = (kkA+1>8)?8:(kkA+1);
        int kh = koff ? KHt[kkB] : KHt[kkA];
        int kw = koff ? KWt[kkB] : KWt[kkA];
        int kkX = koff ? kkB : kkA;

        // hoisted (ciq-invariant) bilinear: weights + corner bases
        int pix = prow*32 + chalf*16 + l15;
        float2 od = *(const float2*)(offl + pix*20 + 2*kkX);
        float py = (float)(row + kh - 1) + od.x;
        float px = (float)(cb + l15 + kw - 1) + od.y;
        float fy = floorf(py), fx = floorf(px);
        float ly = py - fy, lx = px - fx;
        int y0 = (int)fy, x0 = (int)fx;
        int y1 = y0+1, x1 = x0+1;
        bool vy0 = ((unsigned)y0<128u), vy1 = ((unsigned)y1<128u);
        bool vx0 = ((unsigned)x0<128u), vx1 = ((unsigned)x1<128u);
        int y0c = min(max(y0,0),127), y1c = min(max(y1,0),127);
        int x0c = min(max(x0,0),127), x1c = min(max(x1,0),127);
        float f00 = (vy0&&vx0) ? (1.f-ly)*(1.f-lx) : 0.f;
        float f01 = (vy0&&vx1) ? (1.f-ly)*lx       : 0.f;
        float f10 = (vy1&&vx0) ? ly*(1.f-lx)       : 0.f;
        float f11 = (vy1&&vx1) ? ly*lx             : 0.f;
        int e00 = (((y0c<<7)+x0c)<<6) + cih*8;
        int e01 = (((y0c<<7)+x1c)<<6) + cih*8;
        int e10 = (((y1c<<7)+x0c)<<6) + cih*8;
        int e11 = (((y1c<<7)+x1c)<<6) + cih*8;

#pragma unroll
        for (int ciq=0; ciq<4; ++ciq) {
            short8v q00 = *(const short8v*)(xb + e00 + ciq*16);
            short8v q01 = *(const short8v*)(xb + e01 + ciq*16);
            short8v q10 = *(const short8v*)(xb + e10 + ciq*16);
            short8v q11 = *(const short8v*)(xb + e11 + ciq*16);
            float sv[8];
#pragma unroll
            for (int j=0;j<8;j++)
                sv[j] = f00*bf2f((ushort)q00[j]) + f01*bf2f((ushort)q01[j])
                      + f10*bf2f((ushort)q10[j]) + f11*bf2f((ushort)q11[j]);
            short8v afr;
#pragma unroll
            for (int j=0;j<8;j++) afr[j] = (short)f2bf(sv[j]);
            const ushort* wp = dwPk + ciq*10240 + kkp*2048 + koff*1024 + cih*512;
#pragma unroll
            for (int q=0;q<4;q++){
                short4v b0 = *(const short4v*)(wp +       (q*16+l15)*4);
                short4v b1 = *(const short4v*)(wp + 256 + (q*16+l15)*4);
                short8v bb = __builtin_shufflevector(b0,b1,0,1,2,3,4,5,6,7);
                acc[q] = __builtin_amdgcn_mfma_f32_16x16x32_bf16(afr, bb, acc[q], 0,0,0);
            }
        }
    }

    // ================= epilogue: LDS transpose, bf16 store, stats =================
    float* yt  = (float*)smem;               // [32 co][68] f32 = 8704 B (overlays offl)
    float* red = (float*)(smem + 8704);      // 512 f32
#pragma unroll
    for (int half=0; half<2; ++half){
        __syncthreads();   // half0: offl reads done; half1: prev yt reads done
#pragma unroll
        for (int qq=0;qq<2;qq++)
            *(f32x4*)(yt + (qq*16+l15)*68 + prow*32 + chalf*16 + lg*4) = acc[half*2+qq];
        __syncthreads();
        {
            int co = t>>3, pxg = (t&7)*8;        // 32 co x 8 px-groups
            short8v v8;
#pragma unroll
            for (int e=0;e<8;e++) v8[e] = (short)f2bf(yt[co*68 + pxg + e]);
            *(short8v*)(yb + ((((b<<6) + half*32 + co)<<14)
                        + ((h0 + (pxg>>5))<<7) + w0 + (pxg&31))) = v8;
        }
        {
            float s=0.f, s2=0.f;
            int co = t&31, seg = t>>5;           // 8 segs x 8 px
            const float* bp = yt + co*68 + seg*8;
#pragma unroll
            for (int qd=0;qd<8;qd++){ float v = bp[qd]; s += v; s2 += v*v; }
            red[seg*32+co] = s; red[256 + seg*32+co] = s2;
        }
        __syncthreads();
        if (t < 64){
            int vv = t>>5, cc = t&31;
            float a = 0.f;
#pragma unroll
            for (int g=0;g<8;g++) a += red[vv*256 + g*32 + cc];
            atomicAdd(statsL + (bid&7)*128 + vv*64 + half*32 + cc, a);
        }
    }
}

// ---------------- fused normalize + ReLU + epilogue + xT emission ----------------
// Block per (b,yrow). mode bits: 1=write dstF, 2=add addsrc, 4=accumulate dstF, 8=emit xT.
__global__ __launch_bounds__(256) void norm_fuse(
    const ushort* __restrict__ yv, const float* __restrict__ statsL,
    const float* __restrict__ gamma, const float* __restrict__ beta,
    const float* __restrict__ addsrc, float* __restrict__ dstF,
    ushort* __restrict__ xTout, int mode)
{
    __shared__ float scs[64], shs[64];
    __shared__ ushort lt[128*72];
    const int bid = blockIdx.x, t = threadIdx.x;
    const int b = bid>>7, y = bid&127;
    if (t < 64){
        float sum=0.f, ssq=0.f;
#pragma unroll
        for (int s=0;s<8;s++){ sum += statsL[s*128+t]; ssq += statsL[s*128+64+t]; }
        float mean = sum*(1.f/65536.f);
        float var  = ssq*(1.f/65536.f) - mean*mean;
        float inv  = rsqrtf(var + 1e-5f);
        float sc = gamma[t]*inv;
        scs[t] = sc; shs[t] = beta[t] - mean*sc;
    }
    __syncthreads();
#pragma unroll
    for (int i=0;i<4;i++){
        int g = i*256 + t;                   // 1024 groups of 8: ch = g>>4, xg = (g&15)*8
        int ch = g>>4, xg = (g&15)*8;
        long base = (long)(((b<<6)+ch)<<14) + (y<<7) + xg;
        short8v v8 = *(const short8v*)(yv + base);
        float sc = scs[ch], sh = shs[ch];
        float r[8];
#pragma unroll
        for (int e=0;e<8;e++) r[e] = fmaxf(bf2f((ushort)v8[e])*sc+sh, 0.f);
        if (mode & 2) {
            const float4* ap = (const float4*)(addsrc + base);
            float4 a0 = ap[0], a1 = ap[1];
            r[0]+=a0.x; r[1]+=a0.y; r[2]+=a0.z; r[3]+=a0.w;
            r[4]+=a1.x; r[5]+=a1.y; r[6]+=a1.z; r[7]+=a1.w;
        }
        if (mode & 4) {
            const float4* op = (const float4*)(dstF + base);
            float4 a0 = op[0], a1 = op[1];
            r[0]+=a0.x; r[1]+=a0.y; r[2]+=a0.z; r[3]+=a0.w;
            r[4]+=a1.x; r[5]+=a1.y; r[6]+=a1.z; r[7]+=a1.w;
        }
        if (mode & 5) {
            float4* dp = (float4*)(dstF + base);
            dp[0] = make_float4(r[0],r[1],r[2],r[3]);
            dp[1] = make_float4(r[4],r[5],r[6],r[7]);
        }
        if (mode & 8) {
#pragma unroll
            for (int e=0;e<8;e++) lt[(xg+e)*72 + ch] = f2bf(r[e]);
        }
    }
    if (mode & 8) {
        __syncthreads();
        ushort* dp = xTout + (((b<<7)+y)<<13);
#pragma unroll
        for (int i=0;i<4;i++){
            int u = i*256 + t;
            int xx = u>>3, cg = u&7;
            short8v v8 = *(const short8v*)(lt + xx*72 + cg*8);
            *(short8v*)(dp + (xx<<6) + cg*8) = v8;
        }
    }
}

// ---------------- host orchestration ----------------
extern "C" void kernel_launch(void* const* d_in, const int* in_sizes, int n_in,
                              void* d_out, int out_size, void* d_ws, size_t ws_size,
                              hipStream_t stream)
{
    const float* x  = (const float*)d_in[0];
    const float* ow = (const float*)d_in[1];
    const float* ob = (const float*)d_in[2];
    const float* dw = (const float*)d_in[3];
    const float* g  = (const float*)d_in[4];
    const float* be = (const float*)d_in[5];
    float* out = (float*)d_out;

    float*  t4     = (float*)d_ws;            // f32 NTOT
    ushort* ybBf   = (ushort*)(t4 + NTOT);
    ushort* xA     = ybBf + NTOT;
    ushort* xB     = xA + NTOT;
    float*  statsG = (float*)(xB + NTOT);     // 7*1024 f32
    ushort* dwPk   = (ushort*)(statsG + 7*1024);
    ushort* owPk   = dwPk + 286720;

    pack_w<<<1120, 256, 0, stream>>>(dw, ow, dwPk, owPk, statsG);
    transpose_x<<<512, 256, 0, stream>>>(x, xA);

    auto L = [&](int l, const ushort* xin, int mode, const float* adds,
                 float* dst, ushort* xout){
        dcn_layer<<<1024, 256, 0, stream>>>(xin, owPk + l*20480, ob + l*18,
                                            dwPk + l*40960, ybBf, statsG + l*1024);
        norm_fuse<<<512, 256, 0, stream>>>(ybBf, statsG + l*1024, g + l*64, be + l*64,
                                           adds, dst, xout, mode);
    };

    // DAG (L4 hoisted before L0 so x's transpose in xA serves both):
    L(4, xA, 1,  nullptr, t4,  nullptr);   // t4  = relu(L4(x))
    L(0, xA, 8,  nullptr, t4,  xB);        // xB  = T(relu(L0(x)))
    L(1, xB, 10, t4,      t4,  xA);        // xA  = T(relu(L1(.)) + t4)   (out_sum_1)
    L(2, xA, 8,  nullptr, t4,  xB);        // xB  = T(relu(L2(s)))
    L(3, xB, 1,  nullptr, out, nullptr);   // out = relu(L3(.))
    L(5, xA, 5,  nullptr, out, nullptr);   // out += relu(L5(s))
    L(6, xA, 5,  nullptr, out, nullptr);   // out += relu(L6(s))
}

// Round 14
// 565.419 us; speedup vs baseline: 1.1094x; 1.0308x over previous
//
#include <hip/hip_runtime.h>
#include <hip/hip_bf16.h>

#define NTOT 4194304
typedef __attribute__((ext_vector_type(4)))  short short4v;
typedef __attribute__((ext_vector_type(8)))  short short8v;
typedef __attribute__((ext_vector_type(4)))  float f32x4;

__device__ __forceinline__ ushort f2bf(float f){
    __hip_bfloat16 h = __float2bfloat16(f);
    return __bfloat16_as_ushort(h);
}
__device__ __forceinline__ float bf2f(ushort u){
    return __uint_as_float(((unsigned)u)<<16);
}

// ---------------- weight pack: per-lane MFMA B-fragment order, bf16 ----------------
// dwPk[l][ciq4][kkp5][koff2][cih2][jg2][co64][j4]
// owPk[l][ciq4][kkp5][koff2][cih2][jg2][co32][j4]
__global__ __launch_bounds__(256) void pack_w(
    const float* __restrict__ dw, const float* __restrict__ ow,
    ushort* __restrict__ dwPk, ushort* __restrict__ owPk,
    float* __restrict__ statsG)
{
    int i = blockIdx.x*256 + threadIdx.x;
    if (i < 286720) {
        int j = i&3, co = (i>>2)&63, jg=(i>>8)&1, cih=(i>>9)&1, koff=(i>>10)&1;
        int r = i>>11; int kkp = r%5; int r2 = r/5; int ciq = r2&3; int l = r2>>2;
        int kk = kkp*2+koff, ci = ciq*16 + cih*8 + jg*4 + j;
        float v = (kk<9)? dw[((l*64+co)*64+ci)*9+kk] : 0.f;
        dwPk[i] = f2bf(v);
    }
    if (i < 143360) {
        int j = i&3, co = (i>>2)&31, jg=(i>>7)&1, cih=(i>>8)&1, koff=(i>>9)&1;
        int r = i>>10; int kkp = r%5; int r2 = r/5; int ciq = r2&3; int l = r2>>2;
        int kk = kkp*2+koff, ci = ciq*16 + cih*8 + jg*4 + j;
        float v = (kk<9 && co<18)? ow[((l*18+co)*64+ci)*9+kk] : 0.f;
        owPk[i] = f2bf(v);
    }
    if (i < 7*1024) statsG[i] = 0.f;   // zero stats accumulators (capture-safe)
}

// ---------------- one-time transpose: NCHW f32 -> [b][y][x][ci] bf16 ----------------
__global__ __launch_bounds__(256) void transpose_x(
    const float* __restrict__ src, ushort* __restrict__ xT)
{
    __shared__ ushort lds[128*72];   // [x 128][ci 72pad]
    const int bid = blockIdx.x, t = threadIdx.x;
    const int b = bid>>7, y = bid&127;
    const float* sp = src + (b<<20) + (y<<7);
#pragma unroll
    for (int i=0;i<32;i++){
        int lin = i*256 + t;
        int ci = lin>>7, xx = lin&127;
        lds[xx*72 + ci] = f2bf(sp[(ci<<14) + xx]);
    }
    __syncthreads();
    ushort* dp = xT + (((b<<7)+y)<<13);
#pragma unroll
    for (int i=0;i<4;i++){
        int u = i*256 + t;
        int xx = u>>3, cg = u&7;
        short8v v8 = *(const short8v*)(lds + xx*72 + cg*8);
        *(short8v*)(dp + (xx<<6) + cg*8) = v8;
    }
}

// kh/kw tables; index 9 clamps to kk=8 (ghost K-slots carry zero weights)
__constant__ int KHt[10] = {0,0,0,1,1,1,2,2,2,2};
__constant__ int KWt[10] = {0,1,2,0,1,2,0,1,2,2};

// ---------------- fused offset-conv + deformable conv, gather from xT ----------------
// Block: 256 thr = 4 waves; tile 4 rows x 32 cols; wave = 32 px (2 A-frags).
// Grid 512, XCD-bijective decode. Corners gathered b128 from channel-last xT
// (exact reference semantics; clamped coords always valid, validity via weights).
// KEY (r8 vs r9-r13 evidence): occupancy is pinned ~6-8 waves/CU for this kernel
// regardless of grid/LDS/VGPR, so performance tracks PER-WAVE ILP/MLP. Pass 1
// and pass 2 are FULLY unrolled (20 independent load+MFMA groups each); pass-2
// bilinear params precomputed for all 10 (kkp,p) up front (static-indexed).
// waves_per_eu(2,2) grants 256-VGPR budget so the unroll doesn't spill.
// A-frag lane: pixel = p*16+(lane&15); k-slot: kk=2kkp+(lane>>5), ci=ciq*16+8*((lane>>4)&1)+j.
// C/D: col=lane&15 (co), row=(lane>>4)*4+reg (pix).
__global__ __attribute__((amdgpu_flat_work_group_size(256,256), amdgpu_waves_per_eu(2,2)))
void dcn_layer(
    const ushort* __restrict__ xT, const ushort* __restrict__ owPk,
    const float* __restrict__ ob, const ushort* __restrict__ dwPk,
    ushort* __restrict__ yb, float* __restrict__ statsL)
{
    __shared__ __align__(16) char smem[18944];
    float* offl = (float*)smem;              // [128 px][20] f32 = 10240 B

    const int t = threadIdx.x, lane = t&63, w = t>>6;
    const int l15 = lane&15, lg = lane>>4;
    const int cih = lg&1, koff = lane>>5;
    const int bid = blockIdx.x;
    const int xcd = bid&7, idx = bid>>3;
    const int b = xcd>>1, vh = xcd&1;
    const int ht = vh*16 + (idx>>2), wt = idx&3;
    const int w0 = wt*32, h0 = ht*4;
    const int row = h0 + w;
    const ushort* xb = xT + (b<<20);

    // ================= pass 1: offset conv via MFMA (fully unrolled) =================
    f32x4 oacc[2][2];
#pragma unroll
    for (int p=0;p<2;p++)
#pragma unroll
        for (int q=0;q<2;q++) oacc[p][q] = (f32x4){0.f,0.f,0.f,0.f};

    {
        int EB[10]; bool OK[10];
#pragma unroll
        for (int kkp=0; kkp<5; ++kkp) {
            int kkA = 2*kkp;
            int kkB = (kkA+1>8)?8:(kkA+1);
            int kh = koff ? KHt[kkB] : KHt[kkA];
            int kw = koff ? KWt[kkB] : KWt[kkA];
            int gy = row + kh - 1;
            int gyc = min(max(gy,0),127);
            bool vy = ((unsigned)gy<128u);
#pragma unroll
            for (int p=0;p<2;p++){
                int gx = w0 + p*16 + l15 + kw - 1;
                int gxc = min(max(gx,0),127);
                OK[kkp*2+p] = vy && ((unsigned)gx<128u);
                EB[kkp*2+p] = (((gyc<<7)+gxc)<<6) + cih*8;
            }
        }
        const short8v zz = (short8v){0,0,0,0,0,0,0,0};
#pragma unroll
        for (int ciq=0; ciq<4; ++ciq) {
#pragma unroll
            for (int kkp=0; kkp<5; ++kkp) {
                short8v afr[2];
#pragma unroll
                for (int p=0;p<2;p++){
                    short8v q = *(const short8v*)(xb + EB[kkp*2+p] + ciq*16);
                    afr[p] = OK[kkp*2+p] ? q : zz;
                }
                const ushort* wop = owPk + ciq*5120 + kkp*1024 + koff*512 + cih*256;
#pragma unroll
                for (int q2=0;q2<2;q2++){
                    short4v b0 = *(const short4v*)(wop +       (q2*16+l15)*4);
                    short4v b1 = *(const short4v*)(wop + 128 + (q2*16+l15)*4);
                    short8v bb = __builtin_shufflevector(b0,b1,0,1,2,3,4,5,6,7);
#pragma unroll
                    for (int p=0;p<2;p++)
                        oacc[p][q2] = __builtin_amdgcn_mfma_f32_16x16x32_bf16(afr[p], bb, oacc[p][q2], 0,0,0);
                }
            }
        }
    }

    // redistribute offsets: offl[pix 128][20]; only o<18 (stride-20 overflow guard)
    {
        float biasq[2];
#pragma unroll
        for (int q=0;q<2;q++){ int o = q*16+l15; biasq[q] = (o<18)? ob[o] : 0.f; }
#pragma unroll
        for (int p=0;p<2;p++)
#pragma unroll
            for (int q=0;q<2;q++){
                int o = q*16+l15;
                if (o < 18) {
#pragma unroll
                    for (int r=0;r<4;r++){
                        int pix = w*32 + p*16 + lg*4 + r;
                        offl[pix*20 + o] = oacc[p][q][r] + biasq[q];
                    }
                }
            }
    }
    __syncthreads();

    // ================= pass 2: deformable conv via MFMA (fully unrolled) =================
    f32x4 acc[2][4];
#pragma unroll
    for (int p=0;p<2;p++)
#pragma unroll
        for (int q=0;q<4;q++) acc[p][q] = (f32x4){0.f,0.f,0.f,0.f};

    {
        // bilinear params for all 10 (kkp,p) up front -- static-indexed arrays
        float F00[10],F01[10],F10[10],F11[10];
        int   E00[10],E01[10],E10[10],E11[10];
#pragma unroll
        for (int kkp=0; kkp<5; ++kkp) {
            int kkA = 2*kkp;
            int kkB = (kkA+1>8)?8:(kkA+1);
            int kh = koff ? KHt[kkB] : KHt[kkA];
            int kw = koff ? KWt[kkB] : KWt[kkA];
            int kkX = koff ? kkB : kkA;
#pragma unroll
            for (int p=0;p<2;p++){
                int u = kkp*2+p;
                int pix = w*32 + p*16 + l15;
                float2 od = *(const float2*)(offl + pix*20 + 2*kkX);
                float py = (float)(row + kh - 1) + od.x;
                float px = (float)(w0 + p*16 + l15 + kw - 1) + od.y;
                float fy = floorf(py), fx = floorf(px);
                float ly = py - fy, lx = px - fx;
                int y0 = (int)fy, x0 = (int)fx;
                int y1 = y0+1, x1 = x0+1;
                bool vy0 = ((unsigned)y0<128u), vy1 = ((unsigned)y1<128u);
                bool vx0 = ((unsigned)x0<128u), vx1 = ((unsigned)x1<128u);
                int y0c = min(max(y0,0),127), y1c = min(max(y1,0),127);
                int x0c = min(max(x0,0),127), x1c = min(max(x1,0),127);
                F00[u] = (vy0&&vx0) ? (1.f-ly)*(1.f-lx) : 0.f;
                F01[u] = (vy0&&vx1) ? (1.f-ly)*lx       : 0.f;
                F10[u] = (vy1&&vx0) ? ly*(1.f-lx)       : 0.f;
                F11[u] = (vy1&&vx1) ? ly*lx             : 0.f;
                E00[u] = (((y0c<<7)+x0c)<<6) + cih*8;
                E01[u] = (((y0c<<7)+x1c)<<6) + cih*8;
                E10[u] = (((y1c<<7)+x0c)<<6) + cih*8;
                E11[u] = (((y1c<<7)+x1c)<<6) + cih*8;
            }
        }

#pragma unroll
        for (int ciq=0; ciq<4; ++ciq) {
#pragma unroll
            for (int kkp=0; kkp<5; ++kkp) {
                short8v afr[2];
#pragma unroll
                for (int p=0;p<2;p++){
                    int u = kkp*2+p;
                    short8v q00 = *(const short8v*)(xb + E00[u] + ciq*16);
                    short8v q01 = *(const short8v*)(xb + E01[u] + ciq*16);
                    short8v q10 = *(const short8v*)(xb + E10[u] + ciq*16);
                    short8v q11 = *(const short8v*)(xb + E11[u] + ciq*16);
                    float sv[8];
#pragma unroll
                    for (int j=0;j<8;j++)
                        sv[j] = F00[u]*bf2f((ushort)q00[j]) + F01[u]*bf2f((ushort)q01[j])
                              + F10[u]*bf2f((ushort)q10[j]) + F11[u]*bf2f((ushort)q11[j]);
#pragma unroll
                    for (int j=0;j<8;j++) afr[p][j] = (short)f2bf(sv[j]);
                }
                const ushort* wp = dwPk + ciq*10240 + kkp*2048 + koff*1024 + cih*512;
#pragma unroll
                for (int q=0;q<4;q++){
                    short4v b0 = *(const short4v*)(wp +       (q*16+l15)*4);
                    short4v b1 = *(const short4v*)(wp + 256 + (q*16+l15)*4);
                    short8v bb = __builtin_shufflevector(b0,b1,0,1,2,3,4,5,6,7);
                    acc[0][q] = __builtin_amdgcn_mfma_f32_16x16x32_bf16(afr[0], bb, acc[0][q], 0,0,0);
                    acc[1][q] = __builtin_amdgcn_mfma_f32_16x16x32_bf16(afr[1], bb, acc[1][q], 0,0,0);
                }
            }
        }
    }

    // ================= epilogue: LDS transpose, bf16 store, stats =================
    float* yt  = (float*)smem;               // [32 co][132] f32 = 16896 B (overlays offl)
    float* red = (float*)(smem + 16896);     // 512 f32
#pragma unroll
    for (int half=0; half<2; ++half){
        __syncthreads();   // half0: offl reads done; half1: prev stats reads done
#pragma unroll
        for (int p=0;p<2;p++)
#pragma unroll
            for (int qq=0;qq<2;qq++)
                *(f32x4*)(yt + (qq*16+l15)*132 + w*32 + p*16 + lg*4) = acc[p][half*2+qq];
        __syncthreads();
#pragma unroll
        for (int i=0;i<2;i++){
            int u = i*256 + t;                   // 512 slots of 8 px
            int co = u>>4, pxg = (u&15)*8;
            short8v v8;
#pragma unroll
            for (int e=0;e<8;e++) v8[e] = (short)f2bf(yt[co*132 + pxg + e]);
            *(short8v*)(yb + ((((b<<6) + half*32 + co)<<14)
                        + ((h0 + (pxg>>5))<<7) + w0 + (pxg&31))) = v8;
        }
        {
            float s=0.f, s2=0.f;
            int co = t&31, seg = t>>5;           // 8 segs x 16 px
            const float* bp = yt + co*132 + seg*16;
#pragma unroll
            for (int qd=0;qd<16;qd++){ float v = bp[qd]; s += v; s2 += v*v; }
            red[seg*32+co] = s; red[256 + seg*32+co] = s2;
        }
        __syncthreads();
        if (t < 64){
            int vv = t>>5, cc = t&31;
            float a = 0.f;
#pragma unroll
            for (int g=0;g<8;g++) a += red[vv*256 + g*32 + cc];
            atomicAdd(statsL + (bid&7)*128 + vv*64 + half*32 + cc, a);
        }
    }
}

// ---------------- fused normalize + ReLU + epilogue + xT emission ----------------
// Block per (b,yrow). mode bits: 1=write dstF, 2=add addsrc, 4=accumulate dstF, 8=emit xT.
__global__ __launch_bounds__(256) void norm_fuse(
    const ushort* __restrict__ yv, const float* __restrict__ statsL,
    const float* __restrict__ gamma, const float* __restrict__ beta,
    const float* __restrict__ addsrc, float* __restrict__ dstF,
    ushort* __restrict__ xTout, int mode)
{
    __shared__ float scs[64], shs[64];
    __shared__ ushort lt[128*72];
    const int bid = blockIdx.x, t = threadIdx.x;
    const int b = bid>>7, y = bid&127;
    if (t < 64){
        float sum=0.f, ssq=0.f;
#pragma unroll
        for (int s=0;s<8;s++){ sum += statsL[s*128+t]; ssq += statsL[s*128+64+t]; }
        float mean = sum*(1.f/65536.f);
        float var  = ssq*(1.f/65536.f) - mean*mean;
        float inv  = rsqrtf(var + 1e-5f);
        float sc = gamma[t]*inv;
        scs[t] = sc; shs[t] = beta[t] - mean*sc;
    }
    __syncthreads();
#pragma unroll
    for (int i=0;i<4;i++){
        int g = i*256 + t;                   // 1024 groups of 8: ch = g>>4, xg = (g&15)*8
        int ch = g>>4, xg = (g&15)*8;
        long base = (long)(((b<<6)+ch)<<14) + (y<<7) + xg;
        short8v v8 = *(const short8v*)(yv + base);
        float sc = scs[ch], sh = shs[ch];
        float r[8];
#pragma unroll
        for (int e=0;e<8;e++) r[e] = fmaxf(bf2f((ushort)v8[e])*sc+sh, 0.f);
        if (mode & 2) {
            const float4* ap = (const float4*)(addsrc + base);
            float4 a0 = ap[0], a1 = ap[1];
            r[0]+=a0.x; r[1]+=a0.y; r[2]+=a0.z; r[3]+=a0.w;
            r[4]+=a1.x; r[5]+=a1.y; r[6]+=a1.z; r[7]+=a1.w;
        }
        if (mode & 4) {
            const float4* op = (const float4*)(dstF + base);
            float4 a0 = op[0], a1 = op[1];
            r[0]+=a0.x; r[1]+=a0.y; r[2]+=a0.z; r[3]+=a0.w;
            r[4]+=a1.x; r[5]+=a1.y; r[6]+=a1.z; r[7]+=a1.w;
        }
        if (mode & 5) {
            float4* dp = (float4*)(dstF + base);
            dp[0] = make_float4(r[0],r[1],r[2],r[3]);
            dp[1] = make_float4(r[4],r[5],r[6],r[7]);
        }
        if (mode & 8) {
#pragma unroll
            for (int e=0;e<8;e++) lt[(xg+e)*72 + ch] = f2bf(r[e]);
        }
    }
    if (mode & 8) {
        __syncthreads();
        ushort* dp = xTout + (((b<<7)+y)<<13);
#pragma unroll
        for (int i=0;i<4;i++){
            int u = i*256 + t;
            int xx = u>>3, cg = u&7;
            short8v v8 = *(const short8v*)(lt + xx*72 + cg*8);
            *(short8v*)(dp + (xx<<6) + cg*8) = v8;
        }
    }
}

// ---------------- host orchestration ----------------
extern "C" void kernel_launch(void* const* d_in, const int* in_sizes, int n_in,
                              void* d_out, int out_size, void* d_ws, size_t ws_size,
                              hipStream_t stream)
{
    const float* x  = (const float*)d_in[0];
    const float* ow = (const float*)d_in[1];
    const float* ob = (const float*)d_in[2];
    const float* dw = (const float*)d_in[3];
    const float* g  = (const float*)d_in[4];
    const float* be = (const float*)d_in[5];
    float* out = (float*)d_out;

    float*  t4     = (float*)d_ws;            // f32 NTOT
    ushort* ybBf   = (ushort*)(t4 + NTOT);
    ushort* xA     = ybBf + NTOT;
    ushort* xB     = xA + NTOT;
    float*  statsG = (float*)(xB + NTOT);     // 7*1024 f32
    ushort* dwPk   = (ushort*)(statsG + 7*1024);
    ushort* owPk   = dwPk + 286720;

    pack_w<<<1120, 256, 0, stream>>>(dw, ow, dwPk, owPk, statsG);
    transpose_x<<<512, 256, 0, stream>>>(x, xA);

    auto L = [&](int l, const ushort* xin, int mode, const float* adds,
                 float* dst, ushort* xout){
        dcn_layer<<<512, 256, 0, stream>>>(xin, owPk + l*20480, ob + l*18,
                                           dwPk + l*40960, ybBf, statsG + l*1024);
        norm_fuse<<<512, 256, 0, stream>>>(ybBf, statsG + l*1024, g + l*64, be + l*64,
                                           adds, dst, xout, mode);
    };

    // DAG (L4 hoisted before L0 so x's transpose in xA serves both):
    L(4, xA, 1,  nullptr, t4,  nullptr);   // t4  = relu(L4(x))
    L(0, xA, 8,  nullptr, t4,  xB);        // xB  = T(relu(L0(x)))
    L(1, xB, 10, t4,      t4,  xA);        // xA  = T(relu(L1(.)) + t4)   (out_sum_1)
    L(2, xA, 8,  nullptr, t4,  xB);        // xB  = T(relu(L2(s)))
    L(3, xB, 1,  nullptr, out, nullptr);   // out = relu(L3(.))
    L(5, xA, 5,  nullptr, out, nullptr);   // out += relu(L5(s))
    L(6, xA, 5,  nullptr, out, nullptr);   // out += relu(L6(s))
}

// Round 15
// 350.387 us; speedup vs baseline: 1.7903x; 1.6137x over previous
//
#include <hip/hip_runtime.h>
#include <hip/hip_bf16.h>

#define NTOT 4194304
typedef __attribute__((ext_vector_type(4)))  short short4v;
typedef __attribute__((ext_vector_type(8)))  short short8v;
typedef __attribute__((ext_vector_type(4)))  float f32x4;

__device__ __forceinline__ ushort f2bf(float f){
    __hip_bfloat16 h = __float2bfloat16(f);
    return __bfloat16_as_ushort(h);
}
__device__ __forceinline__ float bf2f(ushort u){
    return __uint_as_float(((unsigned)u)<<16);
}

// ---------------- weight pack: per-lane MFMA B-fragment order, bf16 ----------------
// dwPk[l][ciq4][kkp5][koff2][cih2][jg2][co64][j4]
// owPk[l][ciq4][kkp5][koff2][cih2][jg2][co32][j4]
__global__ __launch_bounds__(256) void pack_w(
    const float* __restrict__ dw, const float* __restrict__ ow,
    ushort* __restrict__ dwPk, ushort* __restrict__ owPk,
    float* __restrict__ statsG)
{
    int i = blockIdx.x*256 + threadIdx.x;
    if (i < 286720) {
        int j = i&3, co = (i>>2)&63, jg=(i>>8)&1, cih=(i>>9)&1, koff=(i>>10)&1;
        int r = i>>11; int kkp = r%5; int r2 = r/5; int ciq = r2&3; int l = r2>>2;
        int kk = kkp*2+koff, ci = ciq*16 + cih*8 + jg*4 + j;
        float v = (kk<9)? dw[((l*64+co)*64+ci)*9+kk] : 0.f;
        dwPk[i] = f2bf(v);
    }
    if (i < 143360) {
        int j = i&3, co = (i>>2)&31, jg=(i>>7)&1, cih=(i>>8)&1, koff=(i>>9)&1;
        int r = i>>10; int kkp = r%5; int r2 = r/5; int ciq = r2&3; int l = r2>>2;
        int kk = kkp*2+koff, ci = ciq*16 + cih*8 + jg*4 + j;
        float v = (kk<9 && co<18)? ow[((l*18+co)*64+ci)*9+kk] : 0.f;
        owPk[i] = f2bf(v);
    }
    if (i < 7*1024) statsG[i] = 0.f;   // zero stats accumulators (capture-safe)
}

// ---------------- one-time transpose: NCHW f32 -> [b][y][x][ci] bf16 ----------------
__global__ __launch_bounds__(256) void transpose_x(
    const float* __restrict__ src, ushort* __restrict__ xT)
{
    __shared__ ushort lds[128*72];   // [x 128][ci 72pad]
    const int bid = blockIdx.x, t = threadIdx.x;
    const int b = bid>>7, y = bid&127;
    const float* sp = src + (b<<20) + (y<<7);
#pragma unroll
    for (int i=0;i<32;i++){
        int lin = i*256 + t;
        int ci = lin>>7, xx = lin&127;
        lds[xx*72 + ci] = f2bf(sp[(ci<<14) + xx]);
    }
    __syncthreads();
    ushort* dp = xT + (((b<<7)+y)<<13);
#pragma unroll
    for (int i=0;i<4;i++){
        int u = i*256 + t;
        int xx = u>>3, cg = u&7;
        short8v v8 = *(const short8v*)(lds + xx*72 + cg*8);
        *(short8v*)(dp + (xx<<6) + cg*8) = v8;
    }
}

// kh/kw tables; index 9 clamps to kk=8 (ghost K-slots carry zero weights)
__constant__ int KHt[10] = {0,0,0,1,1,1,2,2,2,2};
__constant__ int KWt[10] = {0,1,2,0,1,2,0,1,2,2};

// ---------------- fused offset-conv + deformable conv, single LDS stage ----------------
// EXACT round-8 winner structure (55us; best measured) with xT staging upgrade:
// Block: 512 thr = 8 waves; tile 8 rows x 32 cols; wave = 32 px (2 A-frags).
// Grid 256, XCD-bijective decode. LDS xt [spatial 20x48][ci 64] bf16, 16B slot
// XOR-swizzled by (sp&7). Staging = coalesced b128 COPY from channel-last xT
// (zero converts; r8 burned 61K strided dword loads + cvts per block here).
// Both ciq and kkp loops unroll-1 with bilinear recomputed per iter: that
// "redundant" VALU is independent work that hides ds_read latency (r8 42%
// VALUBusy @ 88 VGPR beat every hoisted/unrolled variant, r9-r14).
// A-frag lane: pixel = p*16+(lane&15); k-slot: kk=2kkp+(lane>>5), ci=ciq*16+8*((lane>>4)&1)+j.
// C/D: col=lane&15 (co), row=(lane>>4)*4+reg (pix).
__global__ __attribute__((amdgpu_flat_work_group_size(512,512), amdgpu_waves_per_eu(2,2)))
void dcn_layer(
    const ushort* __restrict__ xT, const ushort* __restrict__ owPk,
    const float* __restrict__ ob, const ushort* __restrict__ dwPk,
    ushort* __restrict__ yb, float* __restrict__ statsL)
{
    __shared__ __align__(16) char smem[143360];
    float* offl = (float*)(smem + 122880);       // [256 px][20] f32 = 20480 B

    const int t = threadIdx.x, lane = t&63, w = t>>6;
    const int l15 = lane&15, lg = lane>>4;
    const int cih = lg&1, koff = lane>>5;
    const int bid = blockIdx.x;
    const int xcd = bid&7, idx = bid>>3;
    const int b = xcd>>1, vh = xcd&1;
    const int ht = vh*8 + (idx>>2), wt = idx&3;
    const int w0 = wt*32, h0 = ht*8;
    const int row = h0 + w;
    const int RLO = h0-6, CLO = w0-8;
    const ushort* xb = xT + (b<<20);

    // ================= stage 20x48 x 64ci halo tile: coalesced b128 copy =================
    const short8v zz8 = (short8v){0,0,0,0,0,0,0,0};
#pragma unroll 1
    for (int i=0;i<15;i++){
        int d = i*512 + t;                 // 0..7679 : sp 0..959 x slot 0..7
        int sp = d>>3, slot = d&7;
        int rowt = sp/48, colt = sp - rowt*48;
        int gy = RLO+rowt, gx = CLO+colt;
        bool ok = ((unsigned)gy<128u) && ((unsigned)gx<128u);
        int gyc = min(max(gy,0),127), gxc = min(max(gx,0),127);
        short8v v = *(const short8v*)(xb + (((gyc<<7)+gxc)<<6) + slot*8);
        if (!ok) v = zz8;
        *(short8v*)(smem + sp*128 + ((slot^(sp&7))<<4)) = v;
    }
    __syncthreads();

    // ================= pass 1: offset conv via MFMA (A from LDS) =================
    f32x4 oacc[2][2];
#pragma unroll
    for (int p=0;p<2;p++)
#pragma unroll
        for (int q=0;q<2;q++) oacc[p][q] = (f32x4){0.f,0.f,0.f,0.f};

#pragma unroll 1
    for (int ciq=0; ciq<4; ++ciq) {
#pragma unroll 1
        for (int kkp=0; kkp<5; ++kkp) {
            int kkA = 2*kkp;
            int kkB = (kkA+1>8)?8:(kkA+1);
            int kh = koff ? KHt[kkB] : KHt[kkA];
            int kw = koff ? KWt[kkB] : KWt[kkA];
            short8v afr[2];
#pragma unroll
            for (int p=0;p<2;p++){
                int colt = p*16 + l15 + kw + 7;     // (w0+p*16+l15+kw-1) - CLO
                int rowt = w + 5 + kh;              // (row+kh-1) - RLO
                int sp = rowt*48 + colt;
                int byt = sp*128 + ((((ciq<<1)|cih) ^ (sp&7))<<4);
                afr[p] = *(const short8v*)(smem + byt);
            }
            const ushort* wop = owPk + ciq*5120 + kkp*1024 + koff*512 + cih*256;
#pragma unroll
            for (int q=0;q<2;q++){
                short4v b0 = *(const short4v*)(wop +       (q*16+l15)*4);
                short4v b1 = *(const short4v*)(wop + 128 + (q*16+l15)*4);
                short8v bb = __builtin_shufflevector(b0,b1,0,1,2,3,4,5,6,7);
#pragma unroll
                for (int p=0;p<2;p++)
                    oacc[p][q] = __builtin_amdgcn_mfma_f32_16x16x32_bf16(afr[p], bb, oacc[p][q], 0,0,0);
            }
        }
    }

    // redistribute offsets: offl[pix 256][20]; only o<18 (stride-20 overflow guard)
    {
        float biasq[2];
#pragma unroll
        for (int q=0;q<2;q++){ int o = q*16+l15; biasq[q] = (o<18)? ob[o] : 0.f; }
#pragma unroll
        for (int p=0;p<2;p++)
#pragma unroll
            for (int q=0;q<2;q++){
                int o = q*16+l15;
                if (o < 18) {
#pragma unroll
                    for (int r=0;r<4;r++){
                        int pix = w*32 + p*16 + lg*4 + r;
                        offl[pix*20 + o] = oacc[p][q][r] + biasq[q];
                    }
                }
            }
    }
    __syncthreads();

    // ================= pass 2: deformable conv via MFMA =================
    f32x4 acc[2][4];
#pragma unroll
    for (int p=0;p<2;p++)
#pragma unroll
        for (int q=0;q<4;q++) acc[p][q] = (f32x4){0.f,0.f,0.f,0.f};

#pragma unroll 1
    for (int ciq=0; ciq<4; ++ciq) {
#pragma unroll 1
        for (int kkp=0; kkp<5; ++kkp) {
            int kkA = 2*kkp;
            int kkB = (kkA+1>8)?8:(kkA+1);
            int kh = koff ? KHt[kkB] : KHt[kkA];
            int kw = koff ? KWt[kkB] : KWt[kkA];
            int kkX = koff ? kkB : kkA;
            short8v afr[2];
#pragma unroll
            for (int p=0;p<2;p++){
                int pix = w*32 + p*16 + l15;
                float2 od = *(const float2*)(offl + pix*20 + 2*kkX);
                float py = (float)(row + kh - 1) + od.x;
                float px = (float)(w0 + p*16 + l15 + kw - 1) + od.y;
                float fy = floorf(py), fx = floorf(px);
                float ly = py - fy, lx = px - fx;
                int y0 = (int)fy, x0 = (int)fx;
                int y1 = y0+1, x1 = x0+1;
                bool vy0 = ((unsigned)y0<128u), vy1 = ((unsigned)y1<128u);
                bool vx0 = ((unsigned)x0<128u), vx1 = ((unsigned)x1<128u);
                int y0c = min(max(y0,0),127), y1c = min(max(y1,0),127);
                int x0c = min(max(x0,0),127), x1c = min(max(x1,0),127);
                int r0 = y0c-RLO, r1 = y1c-RLO, c0 = x0c-CLO, c1 = x1c-CLO;
                bool ty0 = ((unsigned)r0<20u), ty1 = ((unsigned)r1<20u);
                bool tx0 = ((unsigned)c0<48u), tx1 = ((unsigned)c1<48u);
                float g00 = (vy0&&vx0) ? (1.f-ly)*(1.f-lx) : 0.f;
                float g01 = (vy0&&vx1) ? (1.f-ly)*lx       : 0.f;
                float g10 = (vy1&&vx0) ? ly*(1.f-lx)       : 0.f;
                float g11 = (vy1&&vx1) ? ly*lx             : 0.f;
                float f00 = (ty0&&tx0) ? g00 : 0.f;
                float f01 = (ty0&&tx1) ? g01 : 0.f;
                float f10 = (ty1&&tx0) ? g10 : 0.f;
                float f11 = (ty1&&tx1) ? g11 : 0.f;
                int rc0 = min(max(r0,0),19), rc1 = min(max(r1,0),19);
                int cc0 = min(max(c0,0),47), cc1 = min(max(c1,0),47);
                int s00 = rc0*48+cc0, s01 = rc0*48+cc1, s10 = rc1*48+cc0, s11 = rc1*48+cc1;
                int slot = (ciq<<1)|cih;
                short8v q00 = *(const short8v*)(smem + s00*128 + ((slot^(s00&7))<<4));
                short8v q01 = *(const short8v*)(smem + s01*128 + ((slot^(s01&7))<<4));
                short8v q10 = *(const short8v*)(smem + s10*128 + ((slot^(s10&7))<<4));
                short8v q11 = *(const short8v*)(smem + s11*128 + ((slot^(s11&7))<<4));
                float sv[8];
#pragma unroll
                for (int j=0;j<8;j++)
                    sv[j] = f00*bf2f((ushort)q00[j]) + f01*bf2f((ushort)q01[j])
                          + f10*bf2f((ushort)q10[j]) + f11*bf2f((ushort)q11[j]);
                // rare fallback: in-image but out-of-tile corners -> b128 from xT
                float r00 = g00-f00, r01 = g01-f01, r10 = g10-f10, r11 = g11-f11;
                if (r00+r01+r10+r11 > 0.f) {
                    int cofs = slot*8;
                    const ushort* g00p = xb + ((((y0c<<7)+x0c)<<6) + cofs);
                    const ushort* g01p = xb + ((((y0c<<7)+x1c)<<6) + cofs);
                    const ushort* g10p = xb + ((((y1c<<7)+x0c)<<6) + cofs);
                    const ushort* g11p = xb + ((((y1c<<7)+x1c)<<6) + cofs);
                    short8v a0 = *(const short8v*)g00p;
                    short8v a1 = *(const short8v*)g01p;
                    short8v a2 = *(const short8v*)g10p;
                    short8v a3 = *(const short8v*)g11p;
#pragma unroll
                    for (int j=0;j<8;j++)
                        sv[j] += r00*bf2f((ushort)a0[j]) + r01*bf2f((ushort)a1[j])
                               + r10*bf2f((ushort)a2[j]) + r11*bf2f((ushort)a3[j]);
                }
#pragma unroll
                for (int j=0;j<8;j++) afr[p][j] = (short)f2bf(sv[j]);
            }
            const ushort* wp = dwPk + ciq*10240 + kkp*2048 + koff*1024 + cih*512;
#pragma unroll
            for (int q=0;q<4;q++){
                short4v b0 = *(const short4v*)(wp +       (q*16+l15)*4);
                short4v b1 = *(const short4v*)(wp + 256 + (q*16+l15)*4);
                short8v bb = __builtin_shufflevector(b0,b1,0,1,2,3,4,5,6,7);
                acc[0][q] = __builtin_amdgcn_mfma_f32_16x16x32_bf16(afr[0], bb, acc[0][q], 0,0,0);
                acc[1][q] = __builtin_amdgcn_mfma_f32_16x16x32_bf16(afr[1], bb, acc[1][q], 0,0,0);
            }
        }
    }

    // ================= epilogue: LDS transpose, bf16 store, stats =================
    float* yt  = (float*)smem;               // [32 co][260] f32 = 33280 B (overlays xt)
    float* red = (float*)(smem + 33280);     // 1024 f32
#pragma unroll
    for (int half=0; half<2; ++half){
        __syncthreads();   // half0: pass-2 tile reads done; half1: prev stats reads done
#pragma unroll
        for (int p=0;p<2;p++)
#pragma unroll
            for (int qq=0;qq<2;qq++)
                *(f32x4*)(yt + (qq*16+l15)*260 + w*32 + p*16 + lg*4) = acc[p][half*2+qq];
        __syncthreads();
#pragma unroll
        for (int i=0;i<2;i++){
            int u = i*512 + t;                   // 0..1023: 32 co x 32 groups of 8 px
            int co = u>>5, px8 = (u&31)*8;
            short8v v8;
#pragma unroll
            for (int e=0;e<8;e++) v8[e] = (short)f2bf(yt[co*260 + px8 + e]);
            *(short8v*)(yb + ((((b<<6) + half*32 + co)<<14)
                        + ((h0 + (px8>>5))<<7) + w0 + (px8&31))) = v8;
        }
        {
            float s=0.f, s2=0.f;
            int co = t&31, seg = t>>5;           // 16 segs x 16 px
            const float* bp = yt + co*260 + seg*16;
#pragma unroll
            for (int qd=0;qd<16;qd++){ float v = bp[qd]; s += v; s2 += v*v; }
            red[seg*32+co] = s; red[512 + seg*32+co] = s2;
        }
        __syncthreads();
        if (t < 64){
            int vv = t>>5, cc = t&31;
            float a = 0.f;
#pragma unroll
            for (int g=0;g<16;g++) a += red[vv*512 + g*32 + cc];
            atomicAdd(statsL + (bid&7)*128 + vv*64 + half*32 + cc, a);
        }
    }
}

// ---------------- fused normalize + ReLU + epilogue + xT emission ----------------
// Block per (b,yrow). mode bits: 1=write dstF, 2=add addsrc, 4=accumulate dstF, 8=emit xT.
__global__ __launch_bounds__(256) void norm_fuse(
    const ushort* __restrict__ yv, const float* __restrict__ statsL,
    const float* __restrict__ gamma, const float* __restrict__ beta,
    const float* __restrict__ addsrc, float* __restrict__ dstF,
    ushort* __restrict__ xTout, int mode)
{
    __shared__ float scs[64], shs[64];
    __shared__ ushort lt[128*72];
    const int bid = blockIdx.x, t = threadIdx.x;
    const int b = bid>>7, y = bid&127;
    if (t < 64){
        float sum=0.f, ssq=0.f;
#pragma unroll
        for (int s=0;s<8;s++){ sum += statsL[s*128+t]; ssq += statsL[s*128+64+t]; }
        float mean = sum*(1.f/65536.f);
        float var  = ssq*(1.f/65536.f) - mean*mean;
        float inv  = rsqrtf(var + 1e-5f);
        float sc = gamma[t]*inv;
        scs[t] = sc; shs[t] = beta[t] - mean*sc;
    }
    __syncthreads();
#pragma unroll
    for (int i=0;i<4;i++){
        int g = i*256 + t;                   // 1024 groups of 8: ch = g>>4, xg = (g&15)*8
        int ch = g>>4, xg = (g&15)*8;
        long base = (long)(((b<<6)+ch)<<14) + (y<<7) + xg;
        short8v v8 = *(const short8v*)(yv + base);
        float sc = scs[ch], sh = shs[ch];
        float r[8];
#pragma unroll
        for (int e=0;e<8;e++) r[e] = fmaxf(bf2f((ushort)v8[e])*sc+sh, 0.f);
        if (mode & 2) {
            const float4* ap = (const float4*)(addsrc + base);
            float4 a0 = ap[0], a1 = ap[1];
            r[0]+=a0.x; r[1]+=a0.y; r[2]+=a0.z; r[3]+=a0.w;
            r[4]+=a1.x; r[5]+=a1.y; r[6]+=a1.z; r[7]+=a1.w;
        }
        if (mode & 4) {
            const float4* op = (const float4*)(dstF + base);
            float4 a0 = op[0], a1 = op[1];
            r[0]+=a0.x; r[1]+=a0.y; r[2]+=a0.z; r[3]+=a0.w;
            r[4]+=a1.x; r[5]+=a1.y; r[6]+=a1.z; r[7]+=a1.w;
        }
        if (mode & 5) {
            float4* dp = (float4*)(dstF + base);
            dp[0] = make_float4(r[0],r[1],r[2],r[3]);
            dp[1] = make_float4(r[4],r[5],r[6],r[7]);
        }
        if (mode & 8) {
#pragma unroll
            for (int e=0;e<8;e++) lt[(xg+e)*72 + ch] = f2bf(r[e]);
        }
    }
    if (mode & 8) {
        __syncthreads();
        ushort* dp = xTout + (((b<<7)+y)<<13);
#pragma unroll
        for (int i=0;i<4;i++){
            int u = i*256 + t;
            int xx = u>>3, cg = u&7;
            short8v v8 = *(const short8v*)(lt + xx*72 + cg*8);
            *(short8v*)(dp + (xx<<6) + cg*8) = v8;
        }
    }
}

// ---------------- host orchestration ----------------
extern "C" void kernel_launch(void* const* d_in, const int* in_sizes, int n_in,
                              void* d_out, int out_size, void* d_ws, size_t ws_size,
                              hipStream_t stream)
{
    const float* x  = (const float*)d_in[0];
    const float* ow = (const float*)d_in[1];
    const float* ob = (const float*)d_in[2];
    const float* dw = (const float*)d_in[3];
    const float* g  = (const float*)d_in[4];
    const float* be = (const float*)d_in[5];
    float* out = (float*)d_out;

    float*  t4     = (float*)d_ws;            // f32 NTOT
    ushort* ybBf   = (ushort*)(t4 + NTOT);
    ushort* xA     = ybBf + NTOT;
    ushort* xB     = xA + NTOT;
    float*  statsG = (float*)(xB + NTOT);     // 7*1024 f32
    ushort* dwPk   = (ushort*)(statsG + 7*1024);
    ushort* owPk   = dwPk + 286720;

    pack_w<<<1120, 256, 0, stream>>>(dw, ow, dwPk, owPk, statsG);
    transpose_x<<<512, 256, 0, stream>>>(x, xA);

    auto L = [&](int l, const ushort* xin, int mode, const float* adds,
                 float* dst, ushort* xout){
        dcn_layer<<<256, 512, 0, stream>>>(xin, owPk + l*20480, ob + l*18,
                                           dwPk + l*40960, ybBf, statsG + l*1024);
        norm_fuse<<<512, 256, 0, stream>>>(ybBf, statsG + l*1024, g + l*64, be + l*64,
                                           adds, dst, xout, mode);
    };

    // DAG (L4 hoisted before L0 so x's transpose in xA serves both):
    L(4, xA, 1,  nullptr, t4,  nullptr);   // t4  = relu(L4(x))
    L(0, xA, 8,  nullptr, t4,  xB);        // xB  = T(relu(L0(x)))
    L(1, xB, 10, t4,      t4,  xA);        // xA  = T(relu(L1(.)) + t4)   (out_sum_1)
    L(2, xA, 8,  nullptr, t4,  xB);        // xB  = T(relu(L2(s)))
    L(3, xB, 1,  nullptr, out, nullptr);   // out = relu(L3(.))
    L(5, xA, 5,  nullptr, out, nullptr);   // out += relu(L5(s))
    L(6, xA, 5,  nullptr, out, nullptr);   // out += relu(L6(s))
}

// Round 16
// 334.049 us; speedup vs baseline: 1.8779x; 1.0489x over previous
//
#include <hip/hip_runtime.h>
#include <hip/hip_bf16.h>
#include <hip/hip_fp16.h>

#define NTOT 4194304
typedef __attribute__((ext_vector_type(4)))  short short4v;
typedef __attribute__((ext_vector_type(8)))  short short8v;
typedef __attribute__((ext_vector_type(4)))  float f32x4;

__device__ __forceinline__ ushort f2bf(float f){
    __hip_bfloat16 h = __float2bfloat16(f);
    return __bfloat16_as_ushort(h);
}
__device__ __forceinline__ float bf2f(ushort u){
    return __uint_as_float(((unsigned)u)<<16);
}

// ---------------- weight pack: per-lane MFMA B-fragment order, bf16 ----------------
// dwPk[l][ciq4][kkp5][koff2][cih2][jg2][co64][j4]
// owPk[l][ciq4][kkp5][koff2][cih2][jg2][co32][j4]
__global__ __launch_bounds__(256) void pack_w(
    const float* __restrict__ dw, const float* __restrict__ ow,
    ushort* __restrict__ dwPk, ushort* __restrict__ owPk,
    float* __restrict__ statsG)
{
    int i = blockIdx.x*256 + threadIdx.x;
    if (i < 286720) {
        int j = i&3, co = (i>>2)&63, jg=(i>>8)&1, cih=(i>>9)&1, koff=(i>>10)&1;
        int r = i>>11; int kkp = r%5; int r2 = r/5; int ciq = r2&3; int l = r2>>2;
        int kk = kkp*2+koff, ci = ciq*16 + cih*8 + jg*4 + j;
        float v = (kk<9)? dw[((l*64+co)*64+ci)*9+kk] : 0.f;
        dwPk[i] = f2bf(v);
    }
    if (i < 143360) {
        int j = i&3, co = (i>>2)&31, jg=(i>>7)&1, cih=(i>>8)&1, koff=(i>>9)&1;
        int r = i>>10; int kkp = r%5; int r2 = r/5; int ciq = r2&3; int l = r2>>2;
        int kk = kkp*2+koff, ci = ciq*16 + cih*8 + jg*4 + j;
        float v = (kk<9 && co<18)? ow[((l*18+co)*64+ci)*9+kk] : 0.f;
        owPk[i] = f2bf(v);
    }
    if (i < 7*1024) statsG[i] = 0.f;   // zero stats accumulators (capture-safe)
}

// ---------------- one-time transpose: NCHW f32 -> [b][y][x][ci] bf16 ----------------
__global__ __launch_bounds__(256) void transpose_x(
    const float* __restrict__ src, ushort* __restrict__ xT)
{
    __shared__ ushort lds[128*72];   // [x 128][ci 72pad]
    const int bid = blockIdx.x, t = threadIdx.x;
    const int b = bid>>7, y = bid&127;
    const float* sp = src + (b<<20) + (y<<7);
#pragma unroll
    for (int i=0;i<32;i++){
        int lin = i*256 + t;
        int ci = lin>>7, xx = lin&127;
        lds[xx*72 + ci] = f2bf(sp[(ci<<14) + xx]);
    }
    __syncthreads();
    ushort* dp = xT + (((b<<7)+y)<<13);
#pragma unroll
    for (int i=0;i<4;i++){
        int u = i*256 + t;
        int xx = u>>3, cg = u&7;
        short8v v8 = *(const short8v*)(lds + xx*72 + cg*8);
        *(short8v*)(dp + (xx<<6) + cg*8) = v8;
    }
}

// kh/kw tables; index 9 clamps to kk=8 (ghost K-slots carry zero weights)
__constant__ int KHt[10] = {0,0,0,1,1,1,2,2,2,2};
__constant__ int KWt[10] = {0,1,2,0,1,2,0,1,2,2};

// ---------------- fused offset-conv + deformable conv, 2-phase ci staging ----------------
// r15 winner structure (44us) with LDS cut below 80KB so 2 blocks/CU fit:
// tile is [18 rows x 48 cols][32 ci] bf16 (80B rows, 4x16B slots, slot^(sp&3)
// swizzle -> conflict-free A-frag reads), staged in TWO ci-phases per pass
// (4 stages total, ~55KB L2 reads each, cheap). Offsets kept fp16 in LDS
// (r9-validated precision). LDS total 79360B.
// PAIR DISPATCH: grid 512 runs two independent layers (bid>>8 selects) ->
// 2 blocks/CU = 16 waves/CU for the {L4,L0} and {L5,L6} DAG pairs; singles
// use grid 256 (identical semantics, both pointer sets equal).
// A-frag lane: pixel = p*16+(lane&15); k-slot: kk=2kkp+(lane>>5), ci=ciq*16+8*((lane>>4)&1)+j.
// C/D: col=lane&15 (co), row=(lane>>4)*4+reg (pix).
__global__ __attribute__((amdgpu_flat_work_group_size(512,512), amdgpu_waves_per_eu(4,8)))
void dcn_layer(
    const ushort* __restrict__ xT,
    const ushort* __restrict__ owPkA, const ushort* __restrict__ owPkB,
    const float*  __restrict__ obA,   const float*  __restrict__ obB,
    const ushort* __restrict__ dwPkA, const ushort* __restrict__ dwPkB,
    ushort* __restrict__ ybA, ushort* __restrict__ ybB,
    float* __restrict__ stA, float* __restrict__ stB)
{
    __shared__ __align__(16) char smem[79360];
    __half* offh = (__half*)(smem + 69120);      // [256 px][20] fp16 = 10240 B

    const int t = threadIdx.x, lane = t&63, w = t>>6;
    const int l15 = lane&15, lg = lane>>4;
    const int cih = lg&1, koff = lane>>5;
    const int bid = blockIdx.x;
    const int lsel = bid >> 8;                   // pair dispatch: layer select
    const int tb = bid & 255;
    const ushort* owPk = lsel ? owPkB : owPkA;
    const float*  ob   = lsel ? obB   : obA;
    const ushort* dwPk = lsel ? dwPkB : dwPkA;
    ushort* yb         = lsel ? ybB   : ybA;
    float*  statsL     = lsel ? stB   : stA;

    const int xcd = tb&7, idx = tb>>3;
    const int b = xcd>>1, vh = xcd&1;
    const int ht = vh*8 + (idx>>2), wt = idx&3;
    const int w0 = wt*32, h0 = ht*8;
    const int row = h0 + w;
    const int RLO = h0-5, CLO = w0-8;            // 18 rows x 48 cols halo
    const ushort* xb = xT + (b<<20);

    const short8v zz8 = (short8v){0,0,0,0,0,0,0,0};
    // stage phase P (ci 32P..32P+31): 864 sp x 4 slots = 3456 b128 writes
    auto stage = [&](int P){
#pragma unroll 1
        for (int i=0;i<7;i++){
            int d = i*512 + t;
            if (d < 3456) {
                int slot = d&3, sp = d>>2;
                int rowt = sp/48, colt = sp - rowt*48;
                int gy = RLO+rowt, gx = CLO+colt;
                bool ok = ((unsigned)gy<128u) && ((unsigned)gx<128u);
                int gyc = min(max(gy,0),127), gxc = min(max(gx,0),127);
                short8v v = *(const short8v*)(xb + (((gyc<<7)+gxc)<<6) + (P*4+slot)*8);
                if (!ok) v = zz8;
                *(short8v*)(smem + sp*80 + ((slot^(sp&3))<<4)) = v;
            }
        }
    };

    // ================= pass 1: offset conv via MFMA (2 ci-phases) =================
    f32x4 oacc[2][2];
#pragma unroll
    for (int p=0;p<2;p++)
#pragma unroll
        for (int q=0;q<2;q++) oacc[p][q] = (f32x4){0.f,0.f,0.f,0.f};

#pragma unroll 1
    for (int P=0; P<2; ++P) {
        if (P) __syncthreads();    // prior phase tile reads done
        stage(P);
        __syncthreads();
#pragma unroll 1
        for (int cil=0; cil<2; ++cil) {
            int ciq = P*2 + cil;
#pragma unroll 1
            for (int kkp=0; kkp<5; ++kkp) {
                int kkA = 2*kkp;
                int kkB = (kkA+1>8)?8:(kkA+1);
                int kh = koff ? KHt[kkB] : KHt[kkA];
                int kw = koff ? KWt[kkB] : KWt[kkA];
                short8v afr[2];
#pragma unroll
                for (int p=0;p<2;p++){
                    int rowt = w + kh + 4;              // (row+kh-1) - RLO
                    int colt = p*16 + l15 + kw + 7;     // (...) - CLO
                    int sp = rowt*48 + colt;
                    int byt = sp*80 + ((((cil<<1)|cih) ^ (sp&3))<<4);
                    afr[p] = *(const short8v*)(smem + byt);
                }
                const ushort* wop = owPk + ciq*5120 + kkp*1024 + koff*512 + cih*256;
#pragma unroll
                for (int q=0;q<2;q++){
                    short4v b0 = *(const short4v*)(wop +       (q*16+l15)*4);
                    short4v b1 = *(const short4v*)(wop + 128 + (q*16+l15)*4);
                    short8v bb = __builtin_shufflevector(b0,b1,0,1,2,3,4,5,6,7);
#pragma unroll
                    for (int p=0;p<2;p++)
                        oacc[p][q] = __builtin_amdgcn_mfma_f32_16x16x32_bf16(afr[p], bb, oacc[p][q], 0,0,0);
                }
            }
        }
    }

    // redistribute offsets fp16: offh[pix 256][20]; only o<18
    {
        float biasq[2];
#pragma unroll
        for (int q=0;q<2;q++){ int o = q*16+l15; biasq[q] = (o<18)? ob[o] : 0.f; }
#pragma unroll
        for (int p=0;p<2;p++)
#pragma unroll
            for (int q=0;q<2;q++){
                int o = q*16+l15;
                if (o < 18) {
#pragma unroll
                    for (int r=0;r<4;r++){
                        int pix = w*32 + p*16 + lg*4 + r;
                        offh[pix*20 + o] = __float2half(oacc[p][q][r] + biasq[q]);
                    }
                }
            }
    }

    // ================= pass 2: deformable conv via MFMA (2 ci-phases) =================
    f32x4 acc[2][4];
#pragma unroll
    for (int p=0;p<2;p++)
#pragma unroll
        for (int q=0;q<4;q++) acc[p][q] = (f32x4){0.f,0.f,0.f,0.f};

#pragma unroll 1
    for (int P=0; P<2; ++P) {
        __syncthreads();   // P0: pass1 reads + offh writes done; P1: pass2-P0 reads done
        stage(P);
        __syncthreads();
#pragma unroll 1
        for (int cil=0; cil<2; ++cil) {
            int ciq = P*2 + cil;
#pragma unroll 1
            for (int kkp=0; kkp<5; ++kkp) {
                int kkA = 2*kkp;
                int kkB = (kkA+1>8)?8:(kkA+1);
                int kh = koff ? KHt[kkB] : KHt[kkA];
                int kw = koff ? KWt[kkB] : KWt[kkA];
                int kkX = koff ? kkB : kkA;
                short8v afr[2];
#pragma unroll
                for (int p=0;p<2;p++){
                    int pix = w*32 + p*16 + l15;
                    unsigned odp = *(const unsigned*)((const char*)offh + pix*40 + 4*kkX);
                    float dy = __half2float(__ushort_as_half((ushort)(odp & 0xffffu)));
                    float dx = __half2float(__ushort_as_half((ushort)(odp >> 16)));
                    float py = (float)(row + kh - 1) + dy;
                    float px = (float)(w0 + p*16 + l15 + kw - 1) + dx;
                    float fy = floorf(py), fx = floorf(px);
                    float ly = py - fy, lx = px - fx;
                    int y0 = (int)fy, x0 = (int)fx;
                    int y1 = y0+1, x1 = x0+1;
                    bool vy0 = ((unsigned)y0<128u), vy1 = ((unsigned)y1<128u);
                    bool vx0 = ((unsigned)x0<128u), vx1 = ((unsigned)x1<128u);
                    int y0c = min(max(y0,0),127), y1c = min(max(y1,0),127);
                    int x0c = min(max(x0,0),127), x1c = min(max(x1,0),127);
                    int r0 = y0c-RLO, r1 = y1c-RLO, c0 = x0c-CLO, c1 = x1c-CLO;
                    bool ty0 = ((unsigned)r0<18u), ty1 = ((unsigned)r1<18u);
                    bool tx0 = ((unsigned)c0<48u), tx1 = ((unsigned)c1<48u);
                    float g00 = (vy0&&vx0) ? (1.f-ly)*(1.f-lx) : 0.f;
                    float g01 = (vy0&&vx1) ? (1.f-ly)*lx       : 0.f;
                    float g10 = (vy1&&vx0) ? ly*(1.f-lx)       : 0.f;
                    float g11 = (vy1&&vx1) ? ly*lx             : 0.f;
                    float f00 = (ty0&&tx0) ? g00 : 0.f;
                    float f01 = (ty0&&tx1) ? g01 : 0.f;
                    float f10 = (ty1&&tx0) ? g10 : 0.f;
                    float f11 = (ty1&&tx1) ? g11 : 0.f;
                    int rc0 = min(max(r0,0),17), rc1 = min(max(r1,0),17);
                    int xc0 = min(max(c0,0),47), xc1 = min(max(c1,0),47);
                    int s00 = rc0*48+xc0, s01 = rc0*48+xc1, s10 = rc1*48+xc0, s11 = rc1*48+xc1;
                    int slo = (cil<<1)|cih;
                    short8v q00 = *(const short8v*)(smem + s00*80 + ((slo^(s00&3))<<4));
                    short8v q01 = *(const short8v*)(smem + s01*80 + ((slo^(s01&3))<<4));
                    short8v q10 = *(const short8v*)(smem + s10*80 + ((slo^(s10&3))<<4));
                    short8v q11 = *(const short8v*)(smem + s11*80 + ((slo^(s11&3))<<4));
                    float sv[8];
#pragma unroll
                    for (int j=0;j<8;j++)
                        sv[j] = f00*bf2f((ushort)q00[j]) + f01*bf2f((ushort)q01[j])
                              + f10*bf2f((ushort)q10[j]) + f11*bf2f((ushort)q11[j]);
                    // rare fallback: in-image but out-of-tile corners -> b128 from xT
                    float r00 = g00-f00, r01 = g01-f01, r10 = g10-f10, r11 = g11-f11;
                    if (r00+r01+r10+r11 > 0.f) {
                        int cofs = (ciq*2 + cih)*8;
                        short8v a0 = *(const short8v*)(xb + ((((y0c<<7)+x0c)<<6) + cofs));
                        short8v a1 = *(const short8v*)(xb + ((((y0c<<7)+x1c)<<6) + cofs));
                        short8v a2 = *(const short8v*)(xb + ((((y1c<<7)+x0c)<<6) + cofs));
                        short8v a3 = *(const short8v*)(xb + ((((y1c<<7)+x1c)<<6) + cofs));
#pragma unroll
                        for (int j=0;j<8;j++)
                            sv[j] += r00*bf2f((ushort)a0[j]) + r01*bf2f((ushort)a1[j])
                                   + r10*bf2f((ushort)a2[j]) + r11*bf2f((ushort)a3[j]);
                    }
#pragma unroll
                    for (int j=0;j<8;j++) afr[p][j] = (short)f2bf(sv[j]);
                }
                const ushort* wp = dwPk + ciq*10240 + kkp*2048 + koff*1024 + cih*512;
#pragma unroll
                for (int q=0;q<4;q++){
                    short4v b0 = *(const short4v*)(wp +       (q*16+l15)*4);
                    short4v b1 = *(const short4v*)(wp + 256 + (q*16+l15)*4);
                    short8v bb = __builtin_shufflevector(b0,b1,0,1,2,3,4,5,6,7);
                    acc[0][q] = __builtin_amdgcn_mfma_f32_16x16x32_bf16(afr[0], bb, acc[0][q], 0,0,0);
                    acc[1][q] = __builtin_amdgcn_mfma_f32_16x16x32_bf16(afr[1], bb, acc[1][q], 0,0,0);
                }
            }
        }
    }

    // ================= epilogue: LDS transpose, bf16 store, stats =================
    float* yt  = (float*)smem;               // [32 co][260] f32 = 33280 B (overlays tile)
    float* red = (float*)(smem + 33280);     // 1024 f32
#pragma unroll
    for (int half=0; half<2; ++half){
        __syncthreads();   // half0: pass-2 tile reads done; half1: prev stats reads done
#pragma unroll
        for (int p=0;p<2;p++)
#pragma unroll
            for (int qq=0;qq<2;qq++)
                *(f32x4*)(yt + (qq*16+l15)*260 + w*32 + p*16 + lg*4) = acc[p][half*2+qq];
        __syncthreads();
#pragma unroll
        for (int i=0;i<2;i++){
            int u = i*512 + t;                   // 0..1023: 32 co x 32 groups of 8 px
            int co = u>>5, px8 = (u&31)*8;
            short8v v8;
#pragma unroll
            for (int e=0;e<8;e++) v8[e] = (short)f2bf(yt[co*260 + px8 + e]);
            *(short8v*)(yb + ((((b<<6) + half*32 + co)<<14)
                        + ((h0 + (px8>>5))<<7) + w0 + (px8&31))) = v8;
        }
        {
            float s=0.f, s2=0.f;
            int co = t&31, seg = t>>5;           // 16 segs x 16 px
            const float* bp = yt + co*260 + seg*16;
#pragma unroll
            for (int qd=0;qd<16;qd++){ float v = bp[qd]; s += v; s2 += v*v; }
            red[seg*32+co] = s; red[512 + seg*32+co] = s2;
        }
        __syncthreads();
        if (t < 64){
            int vv = t>>5, cc = t&31;
            float a = 0.f;
#pragma unroll
            for (int g=0;g<16;g++) a += red[vv*512 + g*32 + cc];
            atomicAdd(statsL + (tb&7)*128 + vv*64 + half*32 + cc, a);
        }
    }
}

// ---------------- fused normalize + ReLU + epilogue + xT emission ----------------
// Block per (b,yrow). mode bits: 1=write dstF, 2=add addsrc, 4=accumulate dstF, 8=emit xT.
__global__ __launch_bounds__(256) void norm_fuse(
    const ushort* __restrict__ yv, const float* __restrict__ statsL,
    const float* __restrict__ gamma, const float* __restrict__ beta,
    const float* __restrict__ addsrc, float* __restrict__ dstF,
    ushort* __restrict__ xTout, int mode)
{
    __shared__ float scs[64], shs[64];
    __shared__ ushort lt[128*72];
    const int bid = blockIdx.x, t = threadIdx.x;
    const int b = bid>>7, y = bid&127;
    if (t < 64){
        float sum=0.f, ssq=0.f;
#pragma unroll
        for (int s=0;s<8;s++){ sum += statsL[s*128+t]; ssq += statsL[s*128+64+t]; }
        float mean = sum*(1.f/65536.f);
        float var  = ssq*(1.f/65536.f) - mean*mean;
        float inv  = rsqrtf(var + 1e-5f);
        float sc = gamma[t]*inv;
        scs[t] = sc; shs[t] = beta[t] - mean*sc;
    }
    __syncthreads();
#pragma unroll
    for (int i=0;i<4;i++){
        int g = i*256 + t;
        int ch = g>>4, xg = (g&15)*8;
        long base = (long)(((b<<6)+ch)<<14) + (y<<7) + xg;
        short8v v8 = *(const short8v*)(yv + base);
        float sc = scs[ch], sh = shs[ch];
        float r[8];
#pragma unroll
        for (int e=0;e<8;e++) r[e] = fmaxf(bf2f((ushort)v8[e])*sc+sh, 0.f);
        if (mode & 2) {
            const float4* ap = (const float4*)(addsrc + base);
            float4 a0 = ap[0], a1 = ap[1];
            r[0]+=a0.x; r[1]+=a0.y; r[2]+=a0.z; r[3]+=a0.w;
            r[4]+=a1.x; r[5]+=a1.y; r[6]+=a1.z; r[7]+=a1.w;
        }
        if (mode & 4) {
            const float4* op = (const float4*)(dstF + base);
            float4 a0 = op[0], a1 = op[1];
            r[0]+=a0.x; r[1]+=a0.y; r[2]+=a0.z; r[3]+=a0.w;
            r[4]+=a1.x; r[5]+=a1.y; r[6]+=a1.z; r[7]+=a1.w;
        }
        if (mode & 5) {
            float4* dp = (float4*)(dstF + base);
            dp[0] = make_float4(r[0],r[1],r[2],r[3]);
            dp[1] = make_float4(r[4],r[5],r[6],r[7]);
        }
        if (mode & 8) {
#pragma unroll
            for (int e=0;e<8;e++) lt[(xg+e)*72 + ch] = f2bf(r[e]);
        }
    }
    if (mode & 8) {
        __syncthreads();
        ushort* dp = xTout + (((b<<7)+y)<<13);
#pragma unroll
        for (int i=0;i<4;i++){
            int u = i*256 + t;
            int xx = u>>3, cg = u&7;
            short8v v8 = *(const short8v*)(lt + xx*72 + cg*8);
            *(short8v*)(dp + (xx<<6) + cg*8) = v8;
        }
    }
}

// ---------------- host orchestration ----------------
extern "C" void kernel_launch(void* const* d_in, const int* in_sizes, int n_in,
                              void* d_out, int out_size, void* d_ws, size_t ws_size,
                              hipStream_t stream)
{
    const float* x  = (const float*)d_in[0];
    const float* ow = (const float*)d_in[1];
    const float* ob = (const float*)d_in[2];
    const float* dw = (const float*)d_in[3];
    const float* g  = (const float*)d_in[4];
    const float* be = (const float*)d_in[5];
    float* out = (float*)d_out;

    float*  t4     = (float*)d_ws;            // f32 NTOT
    ushort* yb0    = (ushort*)(t4 + NTOT);
    ushort* yb1    = yb0 + NTOT;
    ushort* xA     = yb1 + NTOT;
    ushort* xB     = xA + NTOT;
    float*  statsG = (float*)(xB + NTOT);     // 7*1024 f32
    ushort* dwPk   = (ushort*)(statsG + 7*1024);
    ushort* owPk   = dwPk + 286720;

    pack_w<<<1120, 256, 0, stream>>>(dw, ow, dwPk, owPk, statsG);
    transpose_x<<<512, 256, 0, stream>>>(x, xA);

    auto OW = [&](int l){ return owPk + l*20480; };
    auto DW = [&](int l){ return dwPk + l*40960; };
    auto ST = [&](int l){ return statsG + l*1024; };

    auto dcn1 = [&](int l, const ushort* xin, ushort* yb){
        dcn_layer<<<256, 512, 0, stream>>>(xin, OW(l),OW(l), ob+l*18,ob+l*18,
                                           DW(l),DW(l), yb,yb, ST(l),ST(l));
    };
    auto dcn2 = [&](int la, int lb, const ushort* xin){
        dcn_layer<<<512, 512, 0, stream>>>(xin, OW(la),OW(lb), ob+la*18,ob+lb*18,
                                           DW(la),DW(lb), yb0,yb1, ST(la),ST(lb));
    };
    auto nf = [&](int l, const ushort* yb, int mode, const float* adds,
                  float* dst, ushort* xout){
        norm_fuse<<<512, 256, 0, stream>>>(yb, ST(l), g + l*64, be + l*64,
                                           adds, dst, xout, mode);
    };

    // DAG: pair {L4,L0} (both read x), singles L1,L2,L3, pair {L5,L6} (both read s)
    dcn2(4, 0, xA);
    nf(4, yb0, 1,  nullptr, t4,  nullptr);   // t4  = relu(L4(x))
    nf(0, yb1, 8,  nullptr, t4,  xB);        // xB  = T(relu(L0(x)))
    dcn1(1, xB, yb0);
    nf(1, yb0, 10, t4,      t4,  xA);        // xA  = T(relu(L1(.)) + t4)  (out_sum_1)
    dcn1(2, xA, yb0);
    nf(2, yb0, 8,  nullptr, t4,  xB);        // xB  = T(relu(L2(s)))
    dcn1(3, xB, yb0);
    nf(3, yb0, 1,  nullptr, out, nullptr);   // out = relu(L3(.))
    dcn2(5, 6, xA);
    nf(5, yb0, 5,  nullptr, out, nullptr);   // out += relu(L5(s))
    nf(6, yb1, 5,  nullptr, out, nullptr);   // out += relu(L6(s))
}

// Round 17
// 317.974 us; speedup vs baseline: 1.9728x; 1.0506x over previous
//
#include <hip/hip_runtime.h>
#include <hip/hip_bf16.h>
#include <hip/hip_fp16.h>

#define NTOT 4194304
typedef __attribute__((ext_vector_type(4)))  short short4v;
typedef __attribute__((ext_vector_type(8)))  short short8v;
typedef __attribute__((ext_vector_type(4)))  float f32x4;
typedef __attribute__((ext_vector_type(2)))  float fx2;
typedef __attribute__((ext_vector_type(4)))  unsigned int uint4v;

__device__ __forceinline__ ushort f2bf(float f){
    __hip_bfloat16 h = __float2bfloat16(f);
    return __bfloat16_as_ushort(h);
}
__device__ __forceinline__ float bf2f(ushort u){
    return __uint_as_float(((unsigned)u)<<16);
}

// ---------------- weight pack: per-lane MFMA B-fragment order, bf16 ----------------
// dwPk[l][ciq4][kkp5][koff2][cih2][jg2][co64][j4]
// owPk[l][ciq4][kkp5][koff2][cih2][jg2][co32][j4]
__global__ __launch_bounds__(256) void pack_w(
    const float* __restrict__ dw, const float* __restrict__ ow,
    ushort* __restrict__ dwPk, ushort* __restrict__ owPk,
    float* __restrict__ statsG)
{
    int i = blockIdx.x*256 + threadIdx.x;
    if (i < 286720) {
        int j = i&3, co = (i>>2)&63, jg=(i>>8)&1, cih=(i>>9)&1, koff=(i>>10)&1;
        int r = i>>11; int kkp = r%5; int r2 = r/5; int ciq = r2&3; int l = r2>>2;
        int kk = kkp*2+koff, ci = ciq*16 + cih*8 + jg*4 + j;
        float v = (kk<9)? dw[((l*64+co)*64+ci)*9+kk] : 0.f;
        dwPk[i] = f2bf(v);
    }
    if (i < 143360) {
        int j = i&3, co = (i>>2)&31, jg=(i>>7)&1, cih=(i>>8)&1, koff=(i>>9)&1;
        int r = i>>10; int kkp = r%5; int r2 = r/5; int ciq = r2&3; int l = r2>>2;
        int kk = kkp*2+koff, ci = ciq*16 + cih*8 + jg*4 + j;
        float v = (kk<9 && co<18)? ow[((l*18+co)*64+ci)*9+kk] : 0.f;
        owPk[i] = f2bf(v);
    }
    if (i < 7*1024) statsG[i] = 0.f;   // zero stats accumulators (capture-safe)
}

// ---------------- one-time transpose: NCHW f32 -> [b][y][x][ci] bf16 ----------------
__global__ __launch_bounds__(256) void transpose_x(
    const float* __restrict__ src, ushort* __restrict__ xT)
{
    __shared__ ushort lds[128*72];   // [x 128][ci 72pad]
    const int bid = blockIdx.x, t = threadIdx.x;
    const int b = bid>>7, y = bid&127;
    const float* sp = src + (b<<20) + (y<<7);
#pragma unroll
    for (int i=0;i<32;i++){
        int lin = i*256 + t;
        int ci = lin>>7, xx = lin&127;
        lds[xx*72 + ci] = f2bf(sp[(ci<<14) + xx]);
    }
    __syncthreads();
    ushort* dp = xT + (((b<<7)+y)<<13);
#pragma unroll
    for (int i=0;i<4;i++){
        int u = i*256 + t;
        int xx = u>>3, cg = u&7;
        short8v v8 = *(const short8v*)(lds + xx*72 + cg*8);
        *(short8v*)(dp + (xx<<6) + cg*8) = v8;
    }
}

// kh/kw tables; index 9 clamps to kk=8 (ghost K-slots carry zero weights)
__constant__ int KHt[10] = {0,0,0,1,1,1,2,2,2,2};
__constant__ int KWt[10] = {0,1,2,0,1,2,0,1,2,2};

// ---------------- fused offset-conv + deformable conv, NP-phase ci staging ----------------
// Template NP: staging phases. NP=2: 32-ci tile, 80B rows, LDS 79360 (pair: 2 blk/CU).
// NP=4: 16-ci tile, 48B rows, LDS 51712 (TRIPLE: 3 blk/CU = 24 waves/CU).
// Multi-layer dispatch: lsel = bid>>8 picks layer {l0,l1,l2}; grid 256/512/768.
// Interp uses f32x2 packed math -> v_pk_fma_f32 (MI355X dual-issue fp32).
// A-frag lane: pixel = p*16+(lane&15); k-slot: kk=2kkp+(lane>>5), ci=ciq*16+8*((lane>>4)&1)+j.
// C/D: col=lane&15 (co), row=(lane>>4)*4+reg (pix).
template<int NP>
__global__ __attribute__((amdgpu_flat_work_group_size(512,512), amdgpu_waves_per_eu(4,8)))
void dcn_layer(
    const ushort* __restrict__ xT, const ushort* __restrict__ owPkB,
    const float* __restrict__ obB, const ushort* __restrict__ dwPkB,
    ushort* __restrict__ ybB, float* __restrict__ statsB,
    int l0, int l1, int l2)
{
    constexpr int RS   = (NP==2)? 80 : 48;       // bytes per spatial row
    constexpr int UPP  = (NP==2)? 4  : 2;        // 16B units per sp (resident ci/8)
    constexpr int SPS  = (NP==2)? 2  : 1;        // log2(UPP)
    constexpr int CPP  = 4/NP;                   // ciq per phase
    constexpr int TILE = 864*RS;
    constexpr int TOTU = 864*UPP;
    constexpr int ITER = (TOTU+511)/512;
    __shared__ __align__(16) char smem[TILE + 10240];
    __half* offh = (__half*)(smem + TILE);       // [256 px][20] fp16

    const int t = threadIdx.x, lane = t&63, w = t>>6;
    const int l15 = lane&15, lg = lane>>4;
    const int cih = lg&1, koff = lane>>5;
    const int bid = blockIdx.x;
    const int lsel = bid >> 8;                   // multi-layer select
    const int tb = bid & 255;
    const int L = (lsel==0)? l0 : ((lsel==1)? l1 : l2);
    const ushort* owPk = owPkB + L*20480;
    const float*  ob   = obB   + L*18;
    const ushort* dwPk = dwPkB + L*40960;
    ushort* yb         = ybB + (size_t)lsel*NTOT;
    float*  statsL     = statsB + L*1024;

    const int xcd = tb&7, idx = tb>>3;
    const int b = xcd>>1, vh = xcd&1;
    const int ht = vh*8 + (idx>>2), wt = idx&3;
    const int w0 = wt*32, h0 = ht*8;
    const int row = h0 + w;
    const int RLO = h0-5, CLO = w0-8;            // 18 rows x 48 cols halo
    const ushort* xb = xT + (b<<20);

    const short8v zz8 = (short8v){0,0,0,0,0,0,0,0};
    auto stage = [&](int P){
#pragma unroll 1
        for (int i=0;i<ITER;i++){
            int d = i*512 + t;
            if (d < TOTU) {
                int slot = d&(UPP-1), sp = d>>SPS;
                int rowt = sp/48, colt = sp - rowt*48;
                int gy = RLO+rowt, gx = CLO+colt;
                bool ok = ((unsigned)gy<128u) && ((unsigned)gx<128u);
                int gyc = min(max(gy,0),127), gxc = min(max(gx,0),127);
                short8v v = *(const short8v*)(xb + (((gyc<<7)+gxc)<<6) + (P*UPP+slot)*8);
                if (!ok) v = zz8;
                *(short8v*)(smem + sp*RS + ((slot^(sp&(UPP-1)))<<4)) = v;
            }
        }
    };

    // ================= pass 1: offset conv via MFMA =================
    f32x4 oacc[2][2];
#pragma unroll
    for (int p=0;p<2;p++)
#pragma unroll
        for (int q=0;q<2;q++) oacc[p][q] = (f32x4){0.f,0.f,0.f,0.f};

#pragma unroll 1
    for (int P=0; P<NP; ++P) {
        if (P) __syncthreads();
        stage(P);
        __syncthreads();
#pragma unroll 1
        for (int cil=0; cil<CPP; ++cil) {
            int ciq = P*CPP + cil;
            int unit = (NP==2)? ((cil<<1)|cih) : cih;
#pragma unroll 1
            for (int kkp=0; kkp<5; ++kkp) {
                int kkA = 2*kkp;
                int kkB = (kkA+1>8)?8:(kkA+1);
                int kh = koff ? KHt[kkB] : KHt[kkA];
                int kw = koff ? KWt[kkB] : KWt[kkA];
                short8v afr[2];
#pragma unroll
                for (int p=0;p<2;p++){
                    int rowt = w + kh + 4;
                    int colt = p*16 + l15 + kw + 7;
                    int sp = rowt*48 + colt;
                    afr[p] = *(const short8v*)(smem + sp*RS + ((unit^(sp&(UPP-1)))<<4));
                }
                const ushort* wop = owPk + ciq*5120 + kkp*1024 + koff*512 + cih*256;
#pragma unroll
                for (int q=0;q<2;q++){
                    short4v b0 = *(const short4v*)(wop +       (q*16+l15)*4);
                    short4v b1 = *(const short4v*)(wop + 128 + (q*16+l15)*4);
                    short8v bb = __builtin_shufflevector(b0,b1,0,1,2,3,4,5,6,7);
#pragma unroll
                    for (int p=0;p<2;p++)
                        oacc[p][q] = __builtin_amdgcn_mfma_f32_16x16x32_bf16(afr[p], bb, oacc[p][q], 0,0,0);
                }
            }
        }
    }

    // redistribute offsets fp16: offh[pix 256][20]; only o<18
    {
        float biasq[2];
#pragma unroll
        for (int q=0;q<2;q++){ int o = q*16+l15; biasq[q] = (o<18)? ob[o] : 0.f; }
#pragma unroll
        for (int p=0;p<2;p++)
#pragma unroll
            for (int q=0;q<2;q++){
                int o = q*16+l15;
                if (o < 18) {
#pragma unroll
                    for (int r=0;r<4;r++){
                        int pix = w*32 + p*16 + lg*4 + r;
                        offh[pix*20 + o] = __float2half(oacc[p][q][r] + biasq[q]);
                    }
                }
            }
    }

    // ================= pass 2: deformable conv via MFMA =================
    f32x4 acc[2][4];
#pragma unroll
    for (int p=0;p<2;p++)
#pragma unroll
        for (int q=0;q<4;q++) acc[p][q] = (f32x4){0.f,0.f,0.f,0.f};

#pragma unroll 1
    for (int P=0; P<NP; ++P) {
        __syncthreads();   // P0: pass1 reads + offh writes done; else prior reads done
        stage(P);
        __syncthreads();
#pragma unroll 1
        for (int cil=0; cil<CPP; ++cil) {
            int ciq = P*CPP + cil;
            int unit = (NP==2)? ((cil<<1)|cih) : cih;
#pragma unroll 1
            for (int kkp=0; kkp<5; ++kkp) {
                int kkA = 2*kkp;
                int kkB = (kkA+1>8)?8:(kkA+1);
                int kh = koff ? KHt[kkB] : KHt[kkA];
                int kw = koff ? KWt[kkB] : KWt[kkA];
                int kkX = koff ? kkB : kkA;
                short8v afr[2];
#pragma unroll
                for (int p=0;p<2;p++){
                    int pix = w*32 + p*16 + l15;
                    unsigned odp = *(const unsigned*)((const char*)offh + pix*40 + 4*kkX);
                    float dy = __half2float(__ushort_as_half((ushort)(odp & 0xffffu)));
                    float dx = __half2float(__ushort_as_half((ushort)(odp >> 16)));
                    float py = (float)(row + kh - 1) + dy;
                    float px = (float)(w0 + p*16 + l15 + kw - 1) + dx;
                    float fy = floorf(py), fx = floorf(px);
                    float ly = py - fy, lx = px - fx;
                    int y0 = (int)fy, x0 = (int)fx;
                    int y1 = y0+1, x1 = x0+1;
                    bool vy0 = ((unsigned)y0<128u), vy1 = ((unsigned)y1<128u);
                    bool vx0 = ((unsigned)x0<128u), vx1 = ((unsigned)x1<128u);
                    int y0c = min(max(y0,0),127), y1c = min(max(y1,0),127);
                    int x0c = min(max(x0,0),127), x1c = min(max(x1,0),127);
                    int r0 = y0c-RLO, r1 = y1c-RLO, c0 = x0c-CLO, c1 = x1c-CLO;
                    bool ty0 = ((unsigned)r0<18u), ty1 = ((unsigned)r1<18u);
                    bool tx0 = ((unsigned)c0<48u), tx1 = ((unsigned)c1<48u);
                    float g00 = (vy0&&vx0) ? (1.f-ly)*(1.f-lx) : 0.f;
                    float g01 = (vy0&&vx1) ? (1.f-ly)*lx       : 0.f;
                    float g10 = (vy1&&vx0) ? ly*(1.f-lx)       : 0.f;
                    float g11 = (vy1&&vx1) ? ly*lx             : 0.f;
                    float f00 = (ty0&&tx0) ? g00 : 0.f;
                    float f01 = (ty0&&tx1) ? g01 : 0.f;
                    float f10 = (ty1&&tx0) ? g10 : 0.f;
                    float f11 = (ty1&&tx1) ? g11 : 0.f;
                    int rc0 = min(max(r0,0),17), rc1 = min(max(r1,0),17);
                    int xc0 = min(max(c0,0),47), xc1 = min(max(c1,0),47);
                    int s00 = rc0*48+xc0, s01 = rc0*48+xc1, s10 = rc1*48+xc0, s11 = rc1*48+xc1;
                    uint4v q00 = *(const uint4v*)(smem + s00*RS + ((unit^(s00&(UPP-1)))<<4));
                    uint4v q01 = *(const uint4v*)(smem + s01*RS + ((unit^(s01&(UPP-1)))<<4));
                    uint4v q10 = *(const uint4v*)(smem + s10*RS + ((unit^(s10&(UPP-1)))<<4));
                    uint4v q11 = *(const uint4v*)(smem + s11*RS + ((unit^(s11&(UPP-1)))<<4));
                    fx2 F00 = {f00,f00}, F01 = {f01,f01}, F10 = {f10,f10}, F11 = {f11,f11};
                    fx2 sv2[4];
#pragma unroll
                    for (int k=0;k<4;k++){
                        fx2 xa = {__uint_as_float(q00[k]<<16), __uint_as_float(q00[k]&0xffff0000u)};
                        fx2 xb2= {__uint_as_float(q01[k]<<16), __uint_as_float(q01[k]&0xffff0000u)};
                        fx2 xc = {__uint_as_float(q10[k]<<16), __uint_as_float(q10[k]&0xffff0000u)};
                        fx2 xd = {__uint_as_float(q11[k]<<16), __uint_as_float(q11[k]&0xffff0000u)};
                        sv2[k] = xa*F00 + xb2*F01 + xc*F10 + xd*F11;   // v_pk_fma_f32
                    }
                    // rare fallback: in-image but out-of-tile corners -> b128 from xT
                    float r00 = g00-f00, r01 = g01-f01, r10 = g10-f10, r11 = g11-f11;
                    if (r00+r01+r10+r11 > 0.f) {
                        int cofs = (ciq*2 + cih)*8;
                        short8v a0 = *(const short8v*)(xb + ((((y0c<<7)+x0c)<<6) + cofs));
                        short8v a1 = *(const short8v*)(xb + ((((y0c<<7)+x1c)<<6) + cofs));
                        short8v a2 = *(const short8v*)(xb + ((((y1c<<7)+x0c)<<6) + cofs));
                        short8v a3 = *(const short8v*)(xb + ((((y1c<<7)+x1c)<<6) + cofs));
#pragma unroll
                        for (int j=0;j<8;j++){
                            float add = r00*bf2f((ushort)a0[j]) + r01*bf2f((ushort)a1[j])
                                      + r10*bf2f((ushort)a2[j]) + r11*bf2f((ushort)a3[j]);
                            if (j&1) sv2[j>>1].y += add; else sv2[j>>1].x += add;
                        }
                    }
#pragma unroll
                    for (int k=0;k<4;k++){
                        afr[p][2*k]   = (short)f2bf(sv2[k].x);
                        afr[p][2*k+1] = (short)f2bf(sv2[k].y);
                    }
                }
                const ushort* wp = dwPk + ciq*10240 + kkp*2048 + koff*1024 + cih*512;
#pragma unroll
                for (int q=0;q<4;q++){
                    short4v b0 = *(const short4v*)(wp +       (q*16+l15)*4);
                    short4v b1 = *(const short4v*)(wp + 256 + (q*16+l15)*4);
                    short8v bb = __builtin_shufflevector(b0,b1,0,1,2,3,4,5,6,7);
                    acc[0][q] = __builtin_amdgcn_mfma_f32_16x16x32_bf16(afr[0], bb, acc[0][q], 0,0,0);
                    acc[1][q] = __builtin_amdgcn_mfma_f32_16x16x32_bf16(afr[1], bb, acc[1][q], 0,0,0);
                }
            }
        }
    }

    // ================= epilogue: LDS transpose, bf16 store, stats =================
    float* yt  = (float*)smem;               // [32 co][260] f32 = 33280 B (overlays tile)
    float* red = (float*)(smem + 33280);     // 1024 f32
#pragma unroll
    for (int half=0; half<2; ++half){
        __syncthreads();
#pragma unroll
        for (int p=0;p<2;p++)
#pragma unroll
            for (int qq=0;qq<2;qq++)
                *(f32x4*)(yt + (qq*16+l15)*260 + w*32 + p*16 + lg*4) = acc[p][half*2+qq];
        __syncthreads();
#pragma unroll
        for (int i=0;i<2;i++){
            int u = i*512 + t;
            int co = u>>5, px8 = (u&31)*8;
            short8v v8;
#pragma unroll
            for (int e=0;e<8;e++) v8[e] = (short)f2bf(yt[co*260 + px8 + e]);
            *(short8v*)(yb + ((((b<<6) + half*32 + co)<<14)
                        + ((h0 + (px8>>5))<<7) + w0 + (px8&31))) = v8;
        }
        {
            float s=0.f, s2=0.f;
            int co = t&31, seg = t>>5;
            const float* bp = yt + co*260 + seg*16;
#pragma unroll
            for (int qd=0;qd<16;qd++){ float v = bp[qd]; s += v; s2 += v*v; }
            red[seg*32+co] = s; red[512 + seg*32+co] = s2;
        }
        __syncthreads();
        if (t < 64){
            int vv = t>>5, cc = t&31;
            float a = 0.f;
#pragma unroll
            for (int g=0;g<16;g++) a += red[vv*512 + g*32 + cc];
            atomicAdd(statsL + (tb&7)*128 + vv*64 + half*32 + cc, a);
        }
    }
}

// ---------------- fused normalize + ReLU + epilogue + xT emission ----------------
// mode bits: 1=write dstF f32, 2=add addB (bf16 NCHW), 4=accum dstF f32,
//            8=emit xT, 16=write dstB (bf16 NCHW).
__global__ __launch_bounds__(256) void norm_fuse(
    const ushort* __restrict__ yv, const float* __restrict__ statsL,
    const float* __restrict__ gamma, const float* __restrict__ beta,
    const ushort* __restrict__ addB, float* __restrict__ dstF,
    ushort* __restrict__ dstB, ushort* __restrict__ xTout, int mode)
{
    __shared__ float scs[64], shs[64];
    __shared__ ushort lt[128*72];
    const int bid = blockIdx.x, t = threadIdx.x;
    const int b = bid>>7, y = bid&127;
    if (t < 64){
        float sum=0.f, ssq=0.f;
#pragma unroll
        for (int s=0;s<8;s++){ sum += statsL[s*128+t]; ssq += statsL[s*128+64+t]; }
        float mean = sum*(1.f/65536.f);
        float var  = ssq*(1.f/65536.f) - mean*mean;
        float inv  = rsqrtf(var + 1e-5f);
        float sc = gamma[t]*inv;
        scs[t] = sc; shs[t] = beta[t] - mean*sc;
    }
    __syncthreads();
#pragma unroll
    for (int i=0;i<4;i++){
        int g = i*256 + t;
        int ch = g>>4, xg = (g&15)*8;
        long base = (long)(((b<<6)+ch)<<14) + (y<<7) + xg;
        short8v v8 = *(const short8v*)(yv + base);
        float sc = scs[ch], sh = shs[ch];
        float r[8];
#pragma unroll
        for (int e=0;e<8;e++) r[e] = fmaxf(bf2f((ushort)v8[e])*sc+sh, 0.f);
        if (mode & 2) {
            short8v a8 = *(const short8v*)(addB + base);
#pragma unroll
            for (int e=0;e<8;e++) r[e] += bf2f((ushort)a8[e]);
        }
        if (mode & 4) {
            const float4* op = (const float4*)(dstF + base);
            float4 a0 = op[0], a1 = op[1];
            r[0]+=a0.x; r[1]+=a0.y; r[2]+=a0.z; r[3]+=a0.w;
            r[4]+=a1.x; r[5]+=a1.y; r[6]+=a1.z; r[7]+=a1.w;
        }
        if (mode & 5) {
            float4* dp = (float4*)(dstF + base);
            dp[0] = make_float4(r[0],r[1],r[2],r[3]);
            dp[1] = make_float4(r[4],r[5],r[6],r[7]);
        }
        if (mode & 16) {
            short8v o8;
#pragma unroll
            for (int e=0;e<8;e++) o8[e] = (short)f2bf(r[e]);
            *(short8v*)(dstB + base) = o8;
        }
        if (mode & 8) {
#pragma unroll
            for (int e=0;e<8;e++) lt[(xg+e)*72 + ch] = f2bf(r[e]);
        }
    }
    if (mode & 8) {
        __syncthreads();
        ushort* dp = xTout + (((b<<7)+y)<<13);
#pragma unroll
        for (int i=0;i<4;i++){
            int u = i*256 + t;
            int xx = u>>3, cg = u&7;
            short8v v8 = *(const short8v*)(lt + xx*72 + cg*8);
            *(short8v*)(dp + (xx<<6) + cg*8) = v8;
        }
    }
}

// ---------------- host orchestration ----------------
extern "C" void kernel_launch(void* const* d_in, const int* in_sizes, int n_in,
                              void* d_out, int out_size, void* d_ws, size_t ws_size,
                              hipStream_t stream)
{
    const float* x  = (const float*)d_in[0];
    const float* ow = (const float*)d_in[1];
    const float* ob = (const float*)d_in[2];
    const float* dw = (const float*)d_in[3];
    const float* g  = (const float*)d_in[4];
    const float* be = (const float*)d_in[5];
    float* out = (float*)d_out;

    ushort* yb     = (ushort*)d_ws;           // 3 x NTOT bf16
    ushort* t4b    = yb + 3*(size_t)NTOT;     // bf16 NCHW
    ushort* xA     = t4b + NTOT;
    ushort* xB     = xA + NTOT;
    float*  statsG = (float*)(xB + NTOT);     // 7*1024 f32
    ushort* dwPk   = (ushort*)(statsG + 7*1024);
    ushort* owPk   = dwPk + 286720;

    pack_w<<<1120, 256, 0, stream>>>(dw, ow, dwPk, owPk, statsG);
    transpose_x<<<512, 256, 0, stream>>>(x, xA);

    auto nf = [&](int l, const ushort* ybp, int mode, const ushort* addB,
                  float* dstF, ushort* dstB, ushort* xout){
        norm_fuse<<<512, 256, 0, stream>>>(ybp, statsG + l*1024, g + l*64, be + l*64,
                                           addB, dstF, dstB, xout, mode);
    };

    // pair {L4,L0}
    dcn_layer<2><<<512, 512, 0, stream>>>(xA, owPk, ob, dwPk, yb, statsG, 4, 0, 4);
    nf(4, yb,        16, nullptr, nullptr, t4b,    nullptr);  // t4b = relu(L4(x))  bf16
    nf(0, yb+NTOT,    8, nullptr, nullptr, nullptr, xB);      // xB  = T(relu(L0(x)))
    // single L1
    dcn_layer<2><<<256, 512, 0, stream>>>(xB, owPk, ob, dwPk, yb, statsG, 1, 1, 1);
    nf(1, yb,        10, t4b,    nullptr, nullptr, xA);       // xA = T(relu(L1)+t4b) = s
    // TRIPLE {L2,L5,L6} (all read s)
    dcn_layer<4><<<768, 512, 0, stream>>>(xA, owPk, ob, dwPk, yb, statsG, 2, 5, 6);
    nf(2, yb,         8, nullptr, nullptr, nullptr, xB);      // xB  = T(relu(L2(s)))
    nf(5, yb+NTOT,    1, nullptr, out,     nullptr, nullptr); // out = relu(L5(s))
    nf(6, yb+2*(size_t)NTOT, 5, nullptr, out, nullptr, nullptr); // out += relu(L6(s))
    // single L3
    dcn_layer<2><<<256, 512, 0, stream>>>(xB, owPk, ob, dwPk, yb, statsG, 3, 3, 3);
    nf(3, yb,         5, nullptr, out,     nullptr, nullptr); // out += relu(L3)
}

// Round 18
// 295.361 us; speedup vs baseline: 2.1238x; 1.0766x over previous
//
#include <hip/hip_runtime.h>
#include <hip/hip_bf16.h>
#include <hip/hip_fp16.h>

#define NTOT 4194304
typedef __attribute__((ext_vector_type(4)))  short short4v;
typedef __attribute__((ext_vector_type(8)))  short short8v;
typedef __attribute__((ext_vector_type(4)))  float f32x4;
typedef __attribute__((ext_vector_type(2)))  float fx2;
typedef __attribute__((ext_vector_type(4)))  unsigned int uint4v;

__device__ __forceinline__ ushort f2bf(float f){
    __hip_bfloat16 h = __float2bfloat16(f);
    return __bfloat16_as_ushort(h);
}
__device__ __forceinline__ float bf2f(ushort u){
    return __uint_as_float(((unsigned)u)<<16);
}

// ---------------- weight pack: per-lane MFMA B-fragment order, bf16 ----------------
// dwPk[l][ciq4][kkp5][koff2][cih2][jg2][co64][j4]
// owPk[l][ciq4][kkp5][koff2][cih2][jg2][co32][j4]
__global__ __launch_bounds__(256) void pack_w(
    const float* __restrict__ dw, const float* __restrict__ ow,
    ushort* __restrict__ dwPk, ushort* __restrict__ owPk,
    float* __restrict__ statsG)
{
    int i = blockIdx.x*256 + threadIdx.x;
    if (i < 286720) {
        int j = i&3, co = (i>>2)&63, jg=(i>>8)&1, cih=(i>>9)&1, koff=(i>>10)&1;
        int r = i>>11; int kkp = r%5; int r2 = r/5; int ciq = r2&3; int l = r2>>2;
        int kk = kkp*2+koff, ci = ciq*16 + cih*8 + jg*4 + j;
        float v = (kk<9)? dw[((l*64+co)*64+ci)*9+kk] : 0.f;
        dwPk[i] = f2bf(v);
    }
    if (i < 143360) {
        int j = i&3, co = (i>>2)&31, jg=(i>>7)&1, cih=(i>>8)&1, koff=(i>>9)&1;
        int r = i>>10; int kkp = r%5; int r2 = r/5; int ciq = r2&3; int l = r2>>2;
        int kk = kkp*2+koff, ci = ciq*16 + cih*8 + jg*4 + j;
        float v = (kk<9 && co<18)? ow[((l*18+co)*64+ci)*9+kk] : 0.f;
        owPk[i] = f2bf(v);
    }
    if (i < 7*1024) statsG[i] = 0.f;   // zero stats accumulators (capture-safe)
}

// ---------------- one-time transpose: NCHW f32 -> [b][y][x][ci] bf16 ----------------
__global__ __launch_bounds__(256) void transpose_x(
    const float* __restrict__ src, ushort* __restrict__ xT)
{
    __shared__ ushort lds[128*72];   // [x 128][ci 72pad]
    const int bid = blockIdx.x, t = threadIdx.x;
    const int b = bid>>7, y = bid&127;
    const float* sp = src + (b<<20) + (y<<7);
#pragma unroll
    for (int i=0;i<32;i++){
        int lin = i*256 + t;
        int ci = lin>>7, xx = lin&127;
        lds[xx*72 + ci] = f2bf(sp[(ci<<14) + xx]);
    }
    __syncthreads();
    ushort* dp = xT + (((b<<7)+y)<<13);
#pragma unroll
    for (int i=0;i<4;i++){
        int u = i*256 + t;
        int xx = u>>3, cg = u&7;
        short8v v8 = *(const short8v*)(lds + xx*72 + cg*8);
        *(short8v*)(dp + (xx<<6) + cg*8) = v8;
    }
}

// kh/kw tables; index 9 clamps to kk=8 (ghost K-slots carry zero weights)
__constant__ int KHt[10] = {0,0,0,1,1,1,2,2,2,2};
__constant__ int KWt[10] = {0,1,2,0,1,2,0,1,2,2};

// ---------------- fused offset-conv + deformable conv, 2-phase ci staging ----------------
// Tile [18 rows x 48 cols][32 ci] bf16 (80B rows, slot^(sp&3) swizzle), staged
// in 2 ci-phases per pass. Offsets fp16 in LDS. LDS 79360B -> 2 blocks/CU.
// PAIR DISPATCH: grid 512 runs two independent layers (lsel = bid>>8), each
// with its OWN x input (xTA/xTB) -> DAG tail {L2,L5} + {L3,L6} all paired.
// LAZY IMAGE MASKING: staged tile holds zeros outside the image, so in-tile
// corners need no image-validity weights; image clamps/compares/g-weights
// live only in the rare execz-skipped out-of-tile fallback branch (~24 VALU
// cut per bilinear block on the hot path).
// Interp = f32x2 packed math (v_pk_fma_f32). A-frag lane: pixel=p*16+(lane&15);
// k-slot: kk=2kkp+(lane>>5), ci=ciq*16+8*((lane>>4)&1)+j.
// C/D: col=lane&15 (co), row=(lane>>4)*4+reg (pix).
__global__ __attribute__((amdgpu_flat_work_group_size(512,512), amdgpu_waves_per_eu(4,8)))
void dcn_layer(
    const ushort* __restrict__ xTA, const ushort* __restrict__ xTB,
    const ushort* __restrict__ owPkB, const float* __restrict__ obB,
    const ushort* __restrict__ dwPkB, ushort* __restrict__ ybB,
    float* __restrict__ statsB, int l0, int l1)
{
    __shared__ __align__(16) char smem[79360];
    __half* offh = (__half*)(smem + 69120);      // [256 px][20] fp16

    const int t = threadIdx.x, lane = t&63, w = t>>6;
    const int l15 = lane&15, lg = lane>>4;
    const int cih = lg&1, koff = lane>>5;
    const int bid = blockIdx.x;
    const int lsel = bid >> 8;
    const int tb = bid & 255;
    const int L = lsel ? l1 : l0;
    const ushort* owPk = owPkB + L*20480;
    const float*  ob   = obB   + L*18;
    const ushort* dwPk = dwPkB + L*40960;
    ushort* yb         = ybB + (size_t)lsel*NTOT;
    float*  statsL     = statsB + L*1024;

    const int xcd = tb&7, idx = tb>>3;
    const int b = xcd>>1, vh = xcd&1;
    const int ht = vh*8 + (idx>>2), wt = idx&3;
    const int w0 = wt*32, h0 = ht*8;
    const int row = h0 + w;
    const int RLO = h0-5, CLO = w0-8;            // 18 rows x 48 cols halo
    const ushort* xb = (lsel ? xTB : xTA) + (b<<20);

    const short8v zz8 = (short8v){0,0,0,0,0,0,0,0};
    auto stage = [&](int P){
#pragma unroll 1
        for (int i=0;i<7;i++){
            int d = i*512 + t;
            if (d < 3456) {
                int slot = d&3, sp = d>>2;
                int rowt = sp/48, colt = sp - rowt*48;
                int gy = RLO+rowt, gx = CLO+colt;
                bool ok = ((unsigned)gy<128u) && ((unsigned)gx<128u);
                int gyc = min(max(gy,0),127), gxc = min(max(gx,0),127);
                short8v v = *(const short8v*)(xb + (((gyc<<7)+gxc)<<6) + (P*4+slot)*8);
                if (!ok) v = zz8;
                *(short8v*)(smem + sp*80 + ((slot^(sp&3))<<4)) = v;
            }
        }
    };

    // ================= pass 1: offset conv via MFMA (2 ci-phases) =================
    f32x4 oacc[2][2];
#pragma unroll
    for (int p=0;p<2;p++)
#pragma unroll
        for (int q=0;q<2;q++) oacc[p][q] = (f32x4){0.f,0.f,0.f,0.f};

#pragma unroll 1
    for (int P=0; P<2; ++P) {
        if (P) __syncthreads();
        stage(P);
        __syncthreads();
#pragma unroll 1
        for (int cil=0; cil<2; ++cil) {
            int ciq = P*2 + cil;
            int unit = (cil<<1)|cih;
#pragma unroll 1
            for (int kkp=0; kkp<5; ++kkp) {
                int kkA = 2*kkp;
                int kkB = (kkA+1>8)?8:(kkA+1);
                int kh = koff ? KHt[kkB] : KHt[kkA];
                int kw = koff ? KWt[kkB] : KWt[kkA];
                short8v afr[2];
#pragma unroll
                for (int p=0;p<2;p++){
                    int rowt = w + kh + 4;
                    int colt = p*16 + l15 + kw + 7;
                    int sp = rowt*48 + colt;
                    afr[p] = *(const short8v*)(smem + sp*80 + ((unit^(sp&3))<<4));
                }
                const ushort* wop = owPk + ciq*5120 + kkp*1024 + koff*512 + cih*256;
#pragma unroll
                for (int q=0;q<2;q++){
                    short4v b0 = *(const short4v*)(wop +       (q*16+l15)*4);
                    short4v b1 = *(const short4v*)(wop + 128 + (q*16+l15)*4);
                    short8v bb = __builtin_shufflevector(b0,b1,0,1,2,3,4,5,6,7);
#pragma unroll
                    for (int p=0;p<2;p++)
                        oacc[p][q] = __builtin_amdgcn_mfma_f32_16x16x32_bf16(afr[p], bb, oacc[p][q], 0,0,0);
                }
            }
        }
    }

    // redistribute offsets fp16: offh[pix 256][20]; only o<18
    {
        float biasq[2];
#pragma unroll
        for (int q=0;q<2;q++){ int o = q*16+l15; biasq[q] = (o<18)? ob[o] : 0.f; }
#pragma unroll
        for (int p=0;p<2;p++)
#pragma unroll
            for (int q=0;q<2;q++){
                int o = q*16+l15;
                if (o < 18) {
#pragma unroll
                    for (int r=0;r<4;r++){
                        int pix = w*32 + p*16 + lg*4 + r;
                        offh[pix*20 + o] = __float2half(oacc[p][q][r] + biasq[q]);
                    }
                }
            }
    }

    // ================= pass 2: deformable conv via MFMA (2 ci-phases) =================
    f32x4 acc[2][4];
#pragma unroll
    for (int p=0;p<2;p++)
#pragma unroll
        for (int q=0;q<4;q++) acc[p][q] = (f32x4){0.f,0.f,0.f,0.f};

#pragma unroll 1
    for (int P=0; P<2; ++P) {
        __syncthreads();   // P0: pass1 reads + offh writes done; P1: pass2-P0 reads done
        stage(P);
        __syncthreads();
#pragma unroll 1
        for (int cil=0; cil<2; ++cil) {
            int ciq = P*2 + cil;
            int unit = (cil<<1)|cih;
#pragma unroll 1
            for (int kkp=0; kkp<5; ++kkp) {
                int kkA = 2*kkp;
                int kkB = (kkA+1>8)?8:(kkA+1);
                int kh = koff ? KHt[kkB] : KHt[kkA];
                int kw = koff ? KWt[kkB] : KWt[kkA];
                int kkX = koff ? kkB : kkA;
                short8v afr[2];
#pragma unroll
                for (int p=0;p<2;p++){
                    int pix = w*32 + p*16 + l15;
                    unsigned odp = *(const unsigned*)((const char*)offh + pix*40 + 4*kkX);
                    float dy = __half2float(__ushort_as_half((ushort)(odp & 0xffffu)));
                    float dx = __half2float(__ushort_as_half((ushort)(odp >> 16)));
                    float py = (float)(row + kh - 1) + dy;
                    float px = (float)(w0 + p*16 + l15 + kw - 1) + dx;
                    float fy = floorf(py), fx = floorf(px);
                    float ly = py - fy, lx = px - fx;
                    int y0 = (int)fy, x0 = (int)fx;
                    int r0 = y0 - RLO, c0 = x0 - CLO;
                    int r1 = r0 + 1,  c1 = c0 + 1;
                    bool ty0 = ((unsigned)r0<18u), ty1 = ((unsigned)r1<18u);
                    bool tx0 = ((unsigned)c0<48u), tx1 = ((unsigned)c1<48u);
                    // tile holds zeros outside image -> raw bilinear weights,
                    // masked only by tile membership (lazy image masking)
                    float w00 = (1.f-ly)*(1.f-lx), w01 = (1.f-ly)*lx;
                    float w10 = ly*(1.f-lx),       w11 = ly*lx;
                    float f00 = (ty0&&tx0)? w00 : 0.f;
                    float f01 = (ty0&&tx1)? w01 : 0.f;
                    float f10 = (ty1&&tx0)? w10 : 0.f;
                    float f11 = (ty1&&tx1)? w11 : 0.f;
                    int rc0 = min(max(r0,0),17), rc1 = min(max(r1,0),17);
                    int xc0 = min(max(c0,0),47), xc1 = min(max(c1,0),47);
                    int s00 = rc0*48+xc0, s01 = rc0*48+xc1, s10 = rc1*48+xc0, s11 = rc1*48+xc1;
                    uint4v q00 = *(const uint4v*)(smem + s00*80 + ((unit^(s00&3))<<4));
                    uint4v q01 = *(const uint4v*)(smem + s01*80 + ((unit^(s01&3))<<4));
                    uint4v q10 = *(const uint4v*)(smem + s10*80 + ((unit^(s10&3))<<4));
                    uint4v q11 = *(const uint4v*)(smem + s11*80 + ((unit^(s11&3))<<4));
                    fx2 F00 = {f00,f00}, F01 = {f01,f01}, F10 = {f10,f10}, F11 = {f11,f11};
                    fx2 sv2[4];
#pragma unroll
                    for (int k=0;k<4;k++){
                        fx2 xa = {__uint_as_float(q00[k]<<16), __uint_as_float(q00[k]&0xffff0000u)};
                        fx2 xb2= {__uint_as_float(q01[k]<<16), __uint_as_float(q01[k]&0xffff0000u)};
                        fx2 xc = {__uint_as_float(q10[k]<<16), __uint_as_float(q10[k]&0xffff0000u)};
                        fx2 xd = {__uint_as_float(q11[k]<<16), __uint_as_float(q11[k]&0xffff0000u)};
                        sv2[k] = xa*F00 + xb2*F01 + xc*F10 + xd*F11;   // v_pk_fma_f32
                    }
                    // lazy fallback: any corner out-of-tile AND sample box
                    // intersects image -> add residual from xT (rare, execz)
                    bool allIn = ty0 && ty1 && tx0 && tx1;
                    bool inY = (y0 >= -1) && (y0 <= 127);
                    bool inX = (x0 >= -1) && (x0 <= 127);
                    if (__builtin_expect(!allIn && inY && inX, 0)) {
                        bool vy0 = ((unsigned)y0<128u), vy1 = ((unsigned)(y0+1)<128u);
                        bool vx0 = ((unsigned)x0<128u), vx1 = ((unsigned)(x0+1)<128u);
                        float rw00 = (vy0&&vx0&&!(ty0&&tx0))? w00 : 0.f;
                        float rw01 = (vy0&&vx1&&!(ty0&&tx1))? w01 : 0.f;
                        float rw10 = (vy1&&vx0&&!(ty1&&tx0))? w10 : 0.f;
                        float rw11 = (vy1&&vx1&&!(ty1&&tx1))? w11 : 0.f;
                        int y0c=min(max(y0,0),127), y1c=min(max(y0+1,0),127);
                        int x0c=min(max(x0,0),127), x1c=min(max(x0+1,0),127);
                        int cofs = (ciq*2 + cih)*8;
                        short8v a0 = *(const short8v*)(xb + ((((y0c<<7)+x0c)<<6) + cofs));
                        short8v a1 = *(const short8v*)(xb + ((((y0c<<7)+x1c)<<6) + cofs));
                        short8v a2 = *(const short8v*)(xb + ((((y1c<<7)+x0c)<<6) + cofs));
                        short8v a3 = *(const short8v*)(xb + ((((y1c<<7)+x1c)<<6) + cofs));
#pragma unroll
                        for (int j=0;j<8;j++){
                            float add = rw00*bf2f((ushort)a0[j]) + rw01*bf2f((ushort)a1[j])
                                      + rw10*bf2f((ushort)a2[j]) + rw11*bf2f((ushort)a3[j]);
                            if (j&1) sv2[j>>1].y += add; else sv2[j>>1].x += add;
                        }
                    }
#pragma unroll
                    for (int k=0;k<4;k++){
                        afr[p][2*k]   = (short)f2bf(sv2[k].x);
                        afr[p][2*k+1] = (short)f2bf(sv2[k].y);
                    }
                }
                const ushort* wp = dwPk + ciq*10240 + kkp*2048 + koff*1024 + cih*512;
#pragma unroll
                for (int q=0;q<4;q++){
                    short4v b0 = *(const short4v*)(wp +       (q*16+l15)*4);
                    short4v b1 = *(const short4v*)(wp + 256 + (q*16+l15)*4);
                    short8v bb = __builtin_shufflevector(b0,b1,0,1,2,3,4,5,6,7);
                    acc[0][q] = __builtin_amdgcn_mfma_f32_16x16x32_bf16(afr[0], bb, acc[0][q], 0,0,0);
                    acc[1][q] = __builtin_amdgcn_mfma_f32_16x16x32_bf16(afr[1], bb, acc[1][q], 0,0,0);
                }
            }
        }
    }

    // ================= epilogue: LDS transpose, bf16 store, stats =================
    float* yt  = (float*)smem;               // [32 co][260] f32 = 33280 B (overlays tile)
    float* red = (float*)(smem + 33280);     // 1024 f32
#pragma unroll
    for (int half=0; half<2; ++half){
        __syncthreads();
#pragma unroll
        for (int p=0;p<2;p++)
#pragma unroll
            for (int qq=0;qq<2;qq++)
                *(f32x4*)(yt + (qq*16+l15)*260 + w*32 + p*16 + lg*4) = acc[p][half*2+qq];
        __syncthreads();
#pragma unroll
        for (int i=0;i<2;i++){
            int u = i*512 + t;
            int co = u>>5, px8 = (u&31)*8;
            short8v v8;
#pragma unroll
            for (int e=0;e<8;e++) v8[e] = (short)f2bf(yt[co*260 + px8 + e]);
            *(short8v*)(yb + ((((b<<6) + half*32 + co)<<14)
                        + ((h0 + (px8>>5))<<7) + w0 + (px8&31))) = v8;
        }
        {
            float s=0.f, s2=0.f;
            int co = t&31, seg = t>>5;
            const float* bp = yt + co*260 + seg*16;
#pragma unroll
            for (int qd=0;qd<16;qd++){ float v = bp[qd]; s += v; s2 += v*v; }
            red[seg*32+co] = s; red[512 + seg*32+co] = s2;
        }
        __syncthreads();
        if (t < 64){
            int vv = t>>5, cc = t&31;
            float a = 0.f;
#pragma unroll
            for (int g=0;g<16;g++) a += red[vv*512 + g*32 + cc];
            atomicAdd(statsL + (tb&7)*128 + vv*64 + half*32 + cc, a);
        }
    }
}

// ---------------- fused normalize + ReLU + epilogue + xT emission ----------------
// mode bits: 1=write dstF f32, 2=add addB (bf16 NCHW), 4=accum dstF f32,
//            8=emit xT, 16=write dstB (bf16 NCHW).
__global__ __launch_bounds__(256) void norm_fuse(
    const ushort* __restrict__ yv, const float* __restrict__ statsL,
    const float* __restrict__ gamma, const float* __restrict__ beta,
    const ushort* __restrict__ addB, float* __restrict__ dstF,
    ushort* __restrict__ dstB, ushort* __restrict__ xTout, int mode)
{
    __shared__ float scs[64], shs[64];
    __shared__ ushort lt[128*72];
    const int bid = blockIdx.x, t = threadIdx.x;
    const int b = bid>>7, y = bid&127;
    if (t < 64){
        float sum=0.f, ssq=0.f;
#pragma unroll
        for (int s=0;s<8;s++){ sum += statsL[s*128+t]; ssq += statsL[s*128+64+t]; }
        float mean = sum*(1.f/65536.f);
        float var  = ssq*(1.f/65536.f) - mean*mean;
        float inv  = rsqrtf(var + 1e-5f);
        float sc = gamma[t]*inv;
        scs[t] = sc; shs[t] = beta[t] - mean*sc;
    }
    __syncthreads();
#pragma unroll
    for (int i=0;i<4;i++){
        int g = i*256 + t;
        int ch = g>>4, xg = (g&15)*8;
        long base = (long)(((b<<6)+ch)<<14) + (y<<7) + xg;
        short8v v8 = *(const short8v*)(yv + base);
        float sc = scs[ch], sh = shs[ch];
        float r[8];
#pragma unroll
        for (int e=0;e<8;e++) r[e] = fmaxf(bf2f((ushort)v8[e])*sc+sh, 0.f);
        if (mode & 2) {
            short8v a8 = *(const short8v*)(addB + base);
#pragma unroll
            for (int e=0;e<8;e++) r[e] += bf2f((ushort)a8[e]);
        }
        if (mode & 4) {
            const float4* op = (const float4*)(dstF + base);
            float4 a0 = op[0], a1 = op[1];
            r[0]+=a0.x; r[1]+=a0.y; r[2]+=a0.z; r[3]+=a0.w;
            r[4]+=a1.x; r[5]+=a1.y; r[6]+=a1.z; r[7]+=a1.w;
        }
        if (mode & 5) {
            float4* dp = (float4*)(dstF + base);
            dp[0] = make_float4(r[0],r[1],r[2],r[3]);
            dp[1] = make_float4(r[4],r[5],r[6],r[7]);
        }
        if (mode & 16) {
            short8v o8;
#pragma unroll
            for (int e=0;e<8;e++) o8[e] = (short)f2bf(r[e]);
            *(short8v*)(dstB + base) = o8;
        }
        if (mode & 8) {
#pragma unroll
            for (int e=0;e<8;e++) lt[(xg+e)*72 + ch] = f2bf(r[e]);
        }
    }
    if (mode & 8) {
        __syncthreads();
        ushort* dp = xTout + (((b<<7)+y)<<13);
#pragma unroll
        for (int i=0;i<4;i++){
            int u = i*256 + t;
            int xx = u>>3, cg = u&7;
            short8v v8 = *(const short8v*)(lt + xx*72 + cg*8);
            *(short8v*)(dp + (xx<<6) + cg*8) = v8;
        }
    }
}

// ---------------- host orchestration ----------------
extern "C" void kernel_launch(void* const* d_in, const int* in_sizes, int n_in,
                              void* d_out, int out_size, void* d_ws, size_t ws_size,
                              hipStream_t stream)
{
    const float* x  = (const float*)d_in[0];
    const float* ow = (const float*)d_in[1];
    const float* ob = (const float*)d_in[2];
    const float* dw = (const float*)d_in[3];
    const float* g  = (const float*)d_in[4];
    const float* be = (const float*)d_in[5];
    float* out = (float*)d_out;

    ushort* yb     = (ushort*)d_ws;           // 2 x NTOT bf16
    ushort* t4b    = yb + 2*(size_t)NTOT;     // bf16 NCHW
    ushort* xA     = t4b + NTOT;
    ushort* xB     = xA + NTOT;
    float*  statsG = (float*)(xB + NTOT);     // 7*1024 f32
    ushort* dwPk   = (ushort*)(statsG + 7*1024);
    ushort* owPk   = dwPk + 286720;

    pack_w<<<1120, 256, 0, stream>>>(dw, ow, dwPk, owPk, statsG);
    transpose_x<<<512, 256, 0, stream>>>(x, xA);

    auto nf = [&](int l, const ushort* ybp, int mode, const ushort* addB,
                  float* dstF, ushort* dstB, ushort* xout){
        norm_fuse<<<512, 256, 0, stream>>>(ybp, statsG + l*1024, g + l*64, be + l*64,
                                           addB, dstF, dstB, xout, mode);
    };

    // pair {L4,L0} (both read x)
    dcn_layer<<<512, 512, 0, stream>>>(xA, xA, owPk, ob, dwPk, yb, statsG, 4, 0);
    nf(4, yb,        16, nullptr, nullptr, t4b,    nullptr);  // t4b = relu(L4(x)) bf16
    nf(0, yb+NTOT,    8, nullptr, nullptr, nullptr, xB);      // xB  = T(relu(L0(x)))
    // single L1
    dcn_layer<<<256, 512, 0, stream>>>(xB, xB, owPk, ob, dwPk, yb, statsG, 1, 1);
    nf(1, yb,        10, t4b,    nullptr, nullptr, xA);       // xA = T(relu(L1)+t4b) = s
    // pair {L2,L5} (both read s)
    dcn_layer<<<512, 512, 0, stream>>>(xA, xA, owPk, ob, dwPk, yb, statsG, 2, 5);
    nf(2, yb,         8, nullptr, nullptr, nullptr, xB);      // xB  = T(relu(L2(s)))
    nf(5, yb+NTOT,    1, nullptr, out,     nullptr, nullptr); // out = relu(L5(s))
    // pair {L3,L6}: L3 reads xB, L6 reads s (xA)
    dcn_layer<<<512, 512, 0, stream>>>(xB, xA, owPk, ob, dwPk, yb, statsG, 3, 6);
    nf(3, yb,         5, nullptr, out,     nullptr, nullptr); // out += relu(L3)
    nf(6, yb+NTOT,    5, nullptr, out,     nullptr, nullptr); // out += relu(L6)
}

// Round 19
// 270.400 us; speedup vs baseline: 2.3199x; 1.0923x over previous
//
#include <hip/hip_runtime.h>
#include <hip/hip_bf16.h>
#include <hip/hip_fp16.h>

#define NTOT 4194304
typedef __attribute__((ext_vector_type(4)))  short short4v;
typedef __attribute__((ext_vector_type(8)))  short short8v;
typedef __attribute__((ext_vector_type(4)))  float f32x4;
typedef __attribute__((ext_vector_type(2)))  float fx2;
typedef __attribute__((ext_vector_type(4)))  unsigned int uint4v;

__device__ __forceinline__ ushort f2bf(float f){
    __hip_bfloat16 h = __float2bfloat16(f);
    return __bfloat16_as_ushort(h);
}
__device__ __forceinline__ float bf2f(ushort u){
    return __uint_as_float(((unsigned)u)<<16);
}

// ---------------- weight pack: per-lane MFMA B-fragment order, bf16 ----------------
__global__ __launch_bounds__(256) void pack_w(
    const float* __restrict__ dw, const float* __restrict__ ow,
    ushort* __restrict__ dwPk, ushort* __restrict__ owPk,
    float* __restrict__ statsG)
{
    int i = blockIdx.x*256 + threadIdx.x;
    if (i < 286720) {
        int j = i&3, co = (i>>2)&63, jg=(i>>8)&1, cih=(i>>9)&1, koff=(i>>10)&1;
        int r = i>>11; int kkp = r%5; int r2 = r/5; int ciq = r2&3; int l = r2>>2;
        int kk = kkp*2+koff, ci = ciq*16 + cih*8 + jg*4 + j;
        float v = (kk<9)? dw[((l*64+co)*64+ci)*9+kk] : 0.f;
        dwPk[i] = f2bf(v);
    }
    if (i < 143360) {
        int j = i&3, co = (i>>2)&31, jg=(i>>7)&1, cih=(i>>8)&1, koff=(i>>9)&1;
        int r = i>>10; int kkp = r%5; int r2 = r/5; int ciq = r2&3; int l = r2>>2;
        int kk = kkp*2+koff, ci = ciq*16 + cih*8 + jg*4 + j;
        float v = (kk<9 && co<18)? ow[((l*18+co)*64+ci)*9+kk] : 0.f;
        owPk[i] = f2bf(v);
    }
    if (i < 7*1024) statsG[i] = 0.f;
}

// ---------------- one-time transpose: NCHW f32 -> [b][y][x][ci] bf16 ----------------
__global__ __launch_bounds__(256) void transpose_x(
    const float* __restrict__ src, ushort* __restrict__ xT)
{
    __shared__ ushort lds[128*72];
    const int bid = blockIdx.x, t = threadIdx.x;
    const int b = bid>>7, y = bid&127;
    const float* sp = src + (b<<20) + (y<<7);
#pragma unroll
    for (int i=0;i<32;i++){
        int lin = i*256 + t;
        int ci = lin>>7, xx = lin&127;
        lds[xx*72 + ci] = f2bf(sp[(ci<<14) + xx]);
    }
    __syncthreads();
    ushort* dp = xT + (((b<<7)+y)<<13);
#pragma unroll
    for (int i=0;i<4;i++){
        int u = i*256 + t;
        int xx = u>>3, cg = u&7;
        short8v v8 = *(const short8v*)(lds + xx*72 + cg*8);
        *(short8v*)(dp + (xx<<6) + cg*8) = v8;
    }
}

__constant__ int KHt[10] = {0,0,0,1,1,1,2,2,2,2};
__constant__ int KWt[10] = {0,1,2,0,1,2,0,1,2,2};

// ---------------- fused offset-conv + deformable conv ----------------
// r18 structure + bilinear-setup HOIST: loop nest P -> kkp -> {setup once} -> cil.
// Per-cil corner addr = pc + (u4 ^ m4)  (swizzle XOR distributes over <<4).
// At 16 waves/CU the r10-era "redundant VALU hides latency" tradeoff flips:
// TLP now covers ds_read latency, so duplicate setup is pure waste.
// Split ybA/ybB output pointers (tail DAG buffer juggling).
__global__ __attribute__((amdgpu_flat_work_group_size(512,512), amdgpu_waves_per_eu(4,8)))
void dcn_layer(
    const ushort* __restrict__ xTA, const ushort* __restrict__ xTB,
    const ushort* __restrict__ owPkB, const float* __restrict__ obB,
    const ushort* __restrict__ dwPkB, ushort* __restrict__ ybA,
    ushort* __restrict__ ybX, float* __restrict__ statsB, int l0, int l1)
{
    __shared__ __align__(16) char smem[79360];
    __half* offh = (__half*)(smem + 69120);      // [256 px][20] fp16

    const int t = threadIdx.x, lane = t&63, w = t>>6;
    const int l15 = lane&15, lg = lane>>4;
    const int cih = lg&1, koff = lane>>5;
    const int bid = blockIdx.x;
    const int lsel = bid >> 8;
    const int tb = bid & 255;
    const int L = lsel ? l1 : l0;
    const ushort* owPk = owPkB + L*20480;
    const float*  ob   = obB   + L*18;
    const ushort* dwPk = dwPkB + L*40960;
    ushort* yb         = lsel ? ybX : ybA;
    float*  statsL     = statsB + L*1024;

    const int xcd = tb&7, idx = tb>>3;
    const int b = xcd>>1, vh = xcd&1;
    const int ht = vh*8 + (idx>>2), wt = idx&3;
    const int w0 = wt*32, h0 = ht*8;
    const int row = h0 + w;
    const int RLO = h0-5, CLO = w0-8;            // 18 x 48 halo
    const ushort* xb = (lsel ? xTB : xTA) + (b<<20);

    const short8v zz8 = (short8v){0,0,0,0,0,0,0,0};
    auto stage = [&](int P){
#pragma unroll 1
        for (int i=0;i<7;i++){
            int d = i*512 + t;
            if (d < 3456) {
                int slot = d&3, sp = d>>2;
                int rowt = sp/48, colt = sp - rowt*48;
                int gy = RLO+rowt, gx = CLO+colt;
                bool ok = ((unsigned)gy<128u) && ((unsigned)gx<128u);
                int gyc = min(max(gy,0),127), gxc = min(max(gx,0),127);
                short8v v = *(const short8v*)(xb + (((gyc<<7)+gxc)<<6) + (P*4+slot)*8);
                if (!ok) v = zz8;
                *(short8v*)(smem + sp*80 + ((slot^(sp&3))<<4)) = v;
            }
        }
    };

    // ================= pass 1: offset conv via MFMA =================
    f32x4 oacc[2][2];
#pragma unroll
    for (int p=0;p<2;p++)
#pragma unroll
        for (int q=0;q<2;q++) oacc[p][q] = (f32x4){0.f,0.f,0.f,0.f};

#pragma unroll 1
    for (int P=0; P<2; ++P) {
        if (P) __syncthreads();
        stage(P);
        __syncthreads();
#pragma unroll 1
        for (int kkp=0; kkp<5; ++kkp) {
            int kkA = 2*kkp;
            int kkB2 = (kkA+1>8)?8:(kkA+1);
            int kh = koff ? KHt[kkB2] : KHt[kkA];
            int kw = koff ? KWt[kkB2] : KWt[kkA];
            int PC[2], M4[2];
#pragma unroll
            for (int p=0;p<2;p++){
                int sp = (w + kh + 4)*48 + (p*16 + l15 + kw + 7);
                PC[p] = sp*80; M4[p] = (sp&3)<<4;
            }
#pragma unroll
            for (int cil=0; cil<2; ++cil) {
                int u4 = (((cil<<1)|cih)<<4);
                short8v afr[2];
#pragma unroll
                for (int p=0;p<2;p++)
                    afr[p] = *(const short8v*)(smem + PC[p] + (u4 ^ M4[p]));
                const ushort* wop = owPk + (P*2+cil)*5120 + kkp*1024 + koff*512 + cih*256;
#pragma unroll
                for (int q=0;q<2;q++){
                    short4v b0 = *(const short4v*)(wop +       (q*16+l15)*4);
                    short4v b1 = *(const short4v*)(wop + 128 + (q*16+l15)*4);
                    short8v bb = __builtin_shufflevector(b0,b1,0,1,2,3,4,5,6,7);
#pragma unroll
                    for (int p=0;p<2;p++)
                        oacc[p][q] = __builtin_amdgcn_mfma_f32_16x16x32_bf16(afr[p], bb, oacc[p][q], 0,0,0);
                }
            }
        }
    }

    // redistribute offsets fp16: offh[pix 256][20]; only o<18
    {
        float biasq[2];
#pragma unroll
        for (int q=0;q<2;q++){ int o = q*16+l15; biasq[q] = (o<18)? ob[o] : 0.f; }
#pragma unroll
        for (int p=0;p<2;p++)
#pragma unroll
            for (int q=0;q<2;q++){
                int o = q*16+l15;
                if (o < 18) {
#pragma unroll
                    for (int r=0;r<4;r++){
                        int pix = w*32 + p*16 + lg*4 + r;
                        offh[pix*20 + o] = __float2half(oacc[p][q][r] + biasq[q]);
                    }
                }
            }
    }

    // ================= pass 2: deformable conv via MFMA =================
    f32x4 acc[2][4];
#pragma unroll
    for (int p=0;p<2;p++)
#pragma unroll
        for (int q=0;q<4;q++) acc[p][q] = (f32x4){0.f,0.f,0.f,0.f};

#pragma unroll 1
    for (int P=0; P<2; ++P) {
        __syncthreads();
        stage(P);
        __syncthreads();
#pragma unroll 1
        for (int kkp=0; kkp<5; ++kkp) {
            int kkA = 2*kkp;
            int kkB2 = (kkA+1>8)?8:(kkA+1);
            int kh = koff ? KHt[kkB2] : KHt[kkA];
            int kw = koff ? KWt[kkB2] : KWt[kkA];
            int kkX = koff ? kkB2 : kkA;
            // ---- hoisted bilinear setup (shared by both cil) ----
            float F00[2],F01[2],F10[2],F11[2];
            int PC0[2],PC1[2],PC2[2],PC3[2], M40[2],M41[2],M42[2],M43[2];
            bool FB[2];
#pragma unroll
            for (int p=0;p<2;p++){
                int pix = w*32 + p*16 + l15;
                unsigned odp = *(const unsigned*)((const char*)offh + pix*40 + 4*kkX);
                float dy = __half2float(__ushort_as_half((ushort)(odp & 0xffffu)));
                float dx = __half2float(__ushort_as_half((ushort)(odp >> 16)));
                float py = (float)(row + kh - 1) + dy;
                float px = (float)(w0 + p*16 + l15 + kw - 1) + dx;
                float fy = floorf(py), fx = floorf(px);
                float ly = py - fy, lx = px - fx;
                int y0 = (int)fy, x0 = (int)fx;
                int r0 = y0 - RLO, c0 = x0 - CLO;
                int r1 = r0 + 1,  c1 = c0 + 1;
                bool ty0 = ((unsigned)r0<18u), ty1 = ((unsigned)r1<18u);
                bool tx0 = ((unsigned)c0<48u), tx1 = ((unsigned)c1<48u);
                float w00 = (1.f-ly)*(1.f-lx), w01 = (1.f-ly)*lx;
                float w10 = ly*(1.f-lx),       w11 = ly*lx;
                F00[p] = (ty0&&tx0)? w00 : 0.f;
                F01[p] = (ty0&&tx1)? w01 : 0.f;
                F10[p] = (ty1&&tx0)? w10 : 0.f;
                F11[p] = (ty1&&tx1)? w11 : 0.f;
                int rc0 = min(max(r0,0),17), rc1 = min(max(r1,0),17);
                int xc0 = min(max(c0,0),47), xc1 = min(max(c1,0),47);
                int s00 = rc0*48+xc0, s01 = rc0*48+xc1, s10 = rc1*48+xc0, s11 = rc1*48+xc1;
                PC0[p]=s00*80; M40[p]=(s00&3)<<4;
                PC1[p]=s01*80; M41[p]=(s01&3)<<4;
                PC2[p]=s10*80; M42[p]=(s10&3)<<4;
                PC3[p]=s11*80; M43[p]=(s11&3)<<4;
                bool allIn = ty0 && ty1 && tx0 && tx1;
                FB[p] = !allIn && (y0>=-1)&&(y0<=127)&&(x0>=-1)&&(x0<=127);
            }
#pragma unroll
            for (int cil=0; cil<2; ++cil) {
                int ciq = P*2 + cil;
                int u4 = (((cil<<1)|cih)<<4);
                short8v afr[2];
#pragma unroll
                for (int p=0;p<2;p++){
                    uint4v q00 = *(const uint4v*)(smem + PC0[p] + (u4^M40[p]));
                    uint4v q01 = *(const uint4v*)(smem + PC1[p] + (u4^M41[p]));
                    uint4v q10 = *(const uint4v*)(smem + PC2[p] + (u4^M42[p]));
                    uint4v q11 = *(const uint4v*)(smem + PC3[p] + (u4^M43[p]));
                    fx2 Fa = {F00[p],F00[p]}, Fb = {F01[p],F01[p]};
                    fx2 Fc = {F10[p],F10[p]}, Fd = {F11[p],F11[p]};
                    fx2 sv2[4];
#pragma unroll
                    for (int k=0;k<4;k++){
                        fx2 xa = {__uint_as_float(q00[k]<<16), __uint_as_float(q00[k]&0xffff0000u)};
                        fx2 xb2= {__uint_as_float(q01[k]<<16), __uint_as_float(q01[k]&0xffff0000u)};
                        fx2 xc = {__uint_as_float(q10[k]<<16), __uint_as_float(q10[k]&0xffff0000u)};
                        fx2 xd = {__uint_as_float(q11[k]<<16), __uint_as_float(q11[k]&0xffff0000u)};
                        sv2[k] = xa*Fa + xb2*Fb + xc*Fc + xd*Fd;   // v_pk_fma_f32
                    }
                    if (__builtin_expect(FB[p], 0)) {
                        // rare out-of-tile: recompute everything locally (execz-skipped)
                        int pix = w*32 + p*16 + l15;
                        unsigned odp = *(const unsigned*)((const char*)offh + pix*40 + 4*kkX);
                        float dy = __half2float(__ushort_as_half((ushort)(odp & 0xffffu)));
                        float dx = __half2float(__ushort_as_half((ushort)(odp >> 16)));
                        float py = (float)(row + kh - 1) + dy;
                        float px = (float)(w0 + p*16 + l15 + kw - 1) + dx;
                        float fy = floorf(py), fx = floorf(px);
                        float ly = py - fy, lx = px - fx;
                        int y0 = (int)fy, x0 = (int)fx;
                        int r0 = y0 - RLO, c0 = x0 - CLO;
                        bool ty0 = ((unsigned)r0<18u), ty1 = ((unsigned)(r0+1)<18u);
                        bool tx0 = ((unsigned)c0<48u), tx1 = ((unsigned)(c0+1)<48u);
                        bool vy0 = ((unsigned)y0<128u), vy1 = ((unsigned)(y0+1)<128u);
                        bool vx0 = ((unsigned)x0<128u), vx1 = ((unsigned)(x0+1)<128u);
                        float w00 = (1.f-ly)*(1.f-lx), w01 = (1.f-ly)*lx;
                        float w10 = ly*(1.f-lx),       w11 = ly*lx;
                        float rw00 = (vy0&&vx0&&!(ty0&&tx0))? w00 : 0.f;
                        float rw01 = (vy0&&vx1&&!(ty0&&tx1))? w01 : 0.f;
                        float rw10 = (vy1&&vx0&&!(ty1&&tx0))? w10 : 0.f;
                        float rw11 = (vy1&&vx1&&!(ty1&&tx1))? w11 : 0.f;
                        int y0c=min(max(y0,0),127), y1c=min(max(y0+1,0),127);
                        int x0c=min(max(x0,0),127), x1c=min(max(x0+1,0),127);
                        int cofs = (ciq*2 + cih)*8;
                        short8v a0 = *(const short8v*)(xb + ((((y0c<<7)+x0c)<<6) + cofs));
                        short8v a1 = *(const short8v*)(xb + ((((y0c<<7)+x1c)<<6) + cofs));
                        short8v a2 = *(const short8v*)(xb + ((((y1c<<7)+x0c)<<6) + cofs));
                        short8v a3 = *(const short8v*)(xb + ((((y1c<<7)+x1c)<<6) + cofs));
#pragma unroll
                        for (int j=0;j<8;j++){
                            float add = rw00*bf2f((ushort)a0[j]) + rw01*bf2f((ushort)a1[j])
                                      + rw10*bf2f((ushort)a2[j]) + rw11*bf2f((ushort)a3[j]);
                            if (j&1) sv2[j>>1].y += add; else sv2[j>>1].x += add;
                        }
                    }
#pragma unroll
                    for (int k=0;k<4;k++){
                        afr[p][2*k]   = (short)f2bf(sv2[k].x);
                        afr[p][2*k+1] = (short)f2bf(sv2[k].y);
                    }
                }
                const ushort* wp = dwPk + ciq*10240 + kkp*2048 + koff*1024 + cih*512;
#pragma unroll
                for (int q=0;q<4;q++){
                    short4v b0 = *(const short4v*)(wp +       (q*16+l15)*4);
                    short4v b1 = *(const short4v*)(wp + 256 + (q*16+l15)*4);
                    short8v bb = __builtin_shufflevector(b0,b1,0,1,2,3,4,5,6,7);
                    acc[0][q] = __builtin_amdgcn_mfma_f32_16x16x32_bf16(afr[0], bb, acc[0][q], 0,0,0);
                    acc[1][q] = __builtin_amdgcn_mfma_f32_16x16x32_bf16(afr[1], bb, acc[1][q], 0,0,0);
                }
            }
        }
    }

    // ================= epilogue: LDS transpose, bf16 store, stats =================
    float* yt  = (float*)smem;               // [32 co][260] f32 (overlays tile)
    float* red = (float*)(smem + 33280);     // 1024 f32
#pragma unroll
    for (int half=0; half<2; ++half){
        __syncthreads();
#pragma unroll
        for (int p=0;p<2;p++)
#pragma unroll
            for (int qq=0;qq<2;qq++)
                *(f32x4*)(yt + (qq*16+l15)*260 + w*32 + p*16 + lg*4) = acc[p][half*2+qq];
        __syncthreads();
#pragma unroll
        for (int i=0;i<2;i++){
            int u = i*512 + t;
            int co = u>>5, px8 = (u&31)*8;
            short8v v8;
#pragma unroll
            for (int e=0;e<8;e++) v8[e] = (short)f2bf(yt[co*260 + px8 + e]);
            *(short8v*)(yb + ((((b<<6) + half*32 + co)<<14)
                        + ((h0 + (px8>>5))<<7) + w0 + (px8&31))) = v8;
        }
        {
            float s=0.f, s2=0.f;
            int co = t&31, seg = t>>5;
            const float* bp = yt + co*260 + seg*16;
#pragma unroll
            for (int qd=0;qd<16;qd++){ float v = bp[qd]; s += v; s2 += v*v; }
            red[seg*32+co] = s; red[512 + seg*32+co] = s2;
        }
        __syncthreads();
        if (t < 64){
            int vv = t>>5, cc = t&31;
            float a = 0.f;
#pragma unroll
            for (int g=0;g<16;g++) a += red[vv*512 + g*32 + cc];
            atomicAdd(statsL + (tb&7)*128 + vv*64 + half*32 + cc, a);
        }
    }
}

// ---------------- fused normalize + ReLU + epilogue + xT emission ----------------
// mode bits: 1=write dstF f32, 2=add addB (bf16 NCHW), 4=accum dstF f32,
//            8=emit xT, 16=write dstB (bf16 NCHW).
__global__ __launch_bounds__(256) void norm_fuse(
    const ushort* __restrict__ yv, const float* __restrict__ statsL,
    const float* __restrict__ gamma, const float* __restrict__ beta,
    const ushort* __restrict__ addB, float* __restrict__ dstF,
    ushort* __restrict__ dstB, ushort* __restrict__ xTout, int mode)
{
    __shared__ float scs[64], shs[64];
    __shared__ ushort lt[128*72];
    const int bid = blockIdx.x, t = threadIdx.x;
    const int b = bid>>7, y = bid&127;
    if (t < 64){
        float sum=0.f, ssq=0.f;
#pragma unroll
        for (int s=0;s<8;s++){ sum += statsL[s*128+t]; ssq += statsL[s*128+64+t]; }
        float mean = sum*(1.f/65536.f);
        float var  = ssq*(1.f/65536.f) - mean*mean;
        float inv  = rsqrtf(var + 1e-5f);
        float sc = gamma[t]*inv;
        scs[t] = sc; shs[t] = beta[t] - mean*sc;
    }
    __syncthreads();
#pragma unroll
    for (int i=0;i<4;i++){
        int g = i*256 + t;
        int ch = g>>4, xg = (g&15)*8;
        long base = (long)(((b<<6)+ch)<<14) + (y<<7) + xg;
        short8v v8 = *(const short8v*)(yv + base);
        float sc = scs[ch], sh = shs[ch];
        float r[8];
#pragma unroll
        for (int e=0;e<8;e++) r[e] = fmaxf(bf2f((ushort)v8[e])*sc+sh, 0.f);
        if (mode & 2) {
            short8v a8 = *(const short8v*)(addB + base);
#pragma unroll
            for (int e=0;e<8;e++) r[e] += bf2f((ushort)a8[e]);
        }
        if (mode & 4) {
            const float4* op = (const float4*)(dstF + base);
            float4 a0 = op[0], a1 = op[1];
            r[0]+=a0.x; r[1]+=a0.y; r[2]+=a0.z; r[3]+=a0.w;
            r[4]+=a1.x; r[5]+=a1.y; r[6]+=a1.z; r[7]+=a1.w;
        }
        if (mode & 5) {
            float4* dp = (float4*)(dstF + base);
            dp[0] = make_float4(r[0],r[1],r[2],r[3]);
            dp[1] = make_float4(r[4],r[5],r[6],r[7]);
        }
        if (mode & 16) {
            short8v o8;
#pragma unroll
            for (int e=0;e<8;e++) o8[e] = (short)f2bf(r[e]);
            *(short8v*)(dstB + base) = o8;
        }
        if (mode & 8) {
#pragma unroll
            for (int e=0;e<8;e++) lt[(xg+e)*72 + ch] = f2bf(r[e]);
        }
    }
    if (mode & 8) {
        __syncthreads();
        ushort* dp = xTout + (((b<<7)+y)<<13);
#pragma unroll
        for (int i=0;i<4;i++){
            int u = i*256 + t;
            int xx = u>>3, cg = u&7;
            short8v v8 = *(const short8v*)(lt + xx*72 + cg*8);
            *(short8v*)(dp + (xx<<6) + cg*8) = v8;
        }
    }
}

// ---------------- final merge: out = relu(ya) + relu(yb) + relu(yc) ----------------
__global__ __launch_bounds__(256) void norm3(
    const ushort* __restrict__ ya, const ushort* __restrict__ ybp,
    const ushort* __restrict__ yc, const float* __restrict__ statsG,
    const float* __restrict__ gamma, const float* __restrict__ beta,
    int la, int lb, int lc, float* __restrict__ out)
{
    __shared__ float sc3[3][64], sh3[3][64];
    const int bid = blockIdx.x, t = threadIdx.x;
    const int b = bid>>7, y = bid&127;
    if (t < 192){
        int set = t>>6, ch = t&63;
        int l = (set==0)? la : ((set==1)? lb : lc);
        const float* st = statsG + l*1024;
        float sum=0.f, ssq=0.f;
#pragma unroll
        for (int s=0;s<8;s++){ sum += st[s*128+ch]; ssq += st[s*128+64+ch]; }
        float mean = sum*(1.f/65536.f);
        float var  = ssq*(1.f/65536.f) - mean*mean;
        float inv  = rsqrtf(var + 1e-5f);
        float sc = gamma[l*64+ch]*inv;
        sc3[set][ch] = sc; sh3[set][ch] = beta[l*64+ch] - mean*sc;
    }
    __syncthreads();
#pragma unroll
    for (int i=0;i<4;i++){
        int g = i*256 + t;
        int ch = g>>4, xg = (g&15)*8;
        long base = (long)(((b<<6)+ch)<<14) + (y<<7) + xg;
        short8v a8 = *(const short8v*)(ya  + base);
        short8v b8 = *(const short8v*)(ybp + base);
        short8v c8 = *(const short8v*)(yc  + base);
        float sa = sc3[0][ch], ha = sh3[0][ch];
        float sb = sc3[1][ch], hb = sh3[1][ch];
        float sc = sc3[2][ch], hc = sh3[2][ch];
        float r[8];
#pragma unroll
        for (int e=0;e<8;e++)
            r[e] = fmaxf(bf2f((ushort)a8[e])*sa+ha, 0.f)
                 + fmaxf(bf2f((ushort)b8[e])*sb+hb, 0.f)
                 + fmaxf(bf2f((ushort)c8[e])*sc+hc, 0.f);
        float4* dp = (float4*)(out + base);
        dp[0] = make_float4(r[0],r[1],r[2],r[3]);
        dp[1] = make_float4(r[4],r[5],r[6],r[7]);
    }
}

// ---------------- host orchestration ----------------
extern "C" void kernel_launch(void* const* d_in, const int* in_sizes, int n_in,
                              void* d_out, int out_size, void* d_ws, size_t ws_size,
                              hipStream_t stream)
{
    const float* x  = (const float*)d_in[0];
    const float* ow = (const float*)d_in[1];
    const float* ob = (const float*)d_in[2];
    const float* dw = (const float*)d_in[3];
    const float* g  = (const float*)d_in[4];
    const float* be = (const float*)d_in[5];
    float* out = (float*)d_out;

    ushort* yb0    = (ushort*)d_ws;
    ushort* yb1    = yb0 + NTOT;
    ushort* t4b    = yb1 + NTOT;
    ushort* xA     = t4b + NTOT;
    ushort* xB     = xA + NTOT;
    float*  statsG = (float*)(xB + NTOT);
    ushort* dwPk   = (ushort*)(statsG + 7*1024);
    ushort* owPk   = dwPk + 286720;

    pack_w<<<1120, 256, 0, stream>>>(dw, ow, dwPk, owPk, statsG);
    transpose_x<<<512, 256, 0, stream>>>(x, xA);

    auto nf = [&](int l, const ushort* ybp, int mode, const ushort* addB,
                  float* dstF, ushort* dstB, ushort* xout){
        norm_fuse<<<512, 256, 0, stream>>>(ybp, statsG + l*1024, g + l*64, be + l*64,
                                           addB, dstF, dstB, xout, mode);
    };

    // pair {L4,L0} (both read x)
    dcn_layer<<<512, 512, 0, stream>>>(xA, xA, owPk, ob, dwPk, yb0, yb1, statsG, 4, 0);
    nf(4, yb0,       16, nullptr, nullptr, t4b,    nullptr);  // t4b = relu(L4(x)) bf16
    nf(0, yb1,        8, nullptr, nullptr, nullptr, xB);      // xB  = T(relu(L0(x)))
    // single L1
    dcn_layer<<<256, 512, 0, stream>>>(xB, xB, owPk, ob, dwPk, yb0, yb0, statsG, 1, 1);
    nf(1, yb0,       10, t4b,    nullptr, nullptr, xA);       // xA = T(relu(L1)+t4b) = s
    // pair {L2,L5} (both read s)
    dcn_layer<<<512, 512, 0, stream>>>(xA, xA, owPk, ob, dwPk, yb0, yb1, statsG, 2, 5);
    nf(2, yb0,        8, nullptr, nullptr, nullptr, xB);      // xB = T(relu(L2(s)))
    // pair {L3,L6}: L3 reads xB -> yb0 (y2 dead); L6 reads s -> t4b (dead)
    dcn_layer<<<512, 512, 0, stream>>>(xB, xA, owPk, ob, dwPk, yb0, t4b, statsG, 3, 6);
    // out = relu(L3) + relu(L5) + relu(L6)  (single pass, no RMW chain)
    norm3<<<512, 256, 0, stream>>>(yb0, yb1, t4b, statsG, g, be, 3, 5, 6, out);
}